// Round 12
// baseline (98.069 us; speedup 1.0000x reference)
//
#include <hip/hip_runtime.h>
#include <hip/hip_bf16.h>
#include <math.h>

#define SEQ   2048
#define DDIM  128
#define NBH   32
#define KVB   64
#define NT    (SEQ / KVB)        // 32 kv tiles
#define QSCALE (0.08838834764831845f * 1.4426950408889634f)  // 1/sqrt(128) * log2(e)

typedef __bf16 bf16x8 __attribute__((ext_vector_type(8)));
typedef float  f32x4  __attribute__((ext_vector_type(4)));
typedef float  f32x16 __attribute__((ext_vector_type(16)));
typedef unsigned short u16x8 __attribute__((ext_vector_type(8)));

// Ks tile: byte = key*256 + off. Read swizzle: 16B-slot ^= key&15 (baked in prep).
__device__ __forceinline__ int swzK(int b) { return b ^ (((b >> 8) & 15) << 4); }
// Vt tile: byte = d*128 + off. slot ^= d&7 (baked into stage source).
__device__ __forceinline__ int swzV(int b) { return b ^ (((b >> 7) & 7) << 4); }

__device__ __forceinline__ void gload16(const void* g, void* l) {
    __builtin_amdgcn_global_load_lds(
        (const __attribute__((address_space(1))) unsigned int*)g,
        (__attribute__((address_space(3))) unsigned int*)l, 16, 0, 0);
}
__device__ __forceinline__ unsigned short bfb(float x) {
    return __builtin_bit_cast(unsigned short, (__bf16)x);
}
__device__ __forceinline__ bf16x8 cvt8s(float4 a, float4 b, float s) {
    bf16x8 v;
    v[0] = (__bf16)(a.x * s); v[1] = (__bf16)(a.y * s);
    v[2] = (__bf16)(a.z * s); v[3] = (__bf16)(a.w * s);
    v[4] = (__bf16)(b.x * s); v[5] = (__bf16)(b.y * s);
    v[6] = (__bf16)(b.z * s); v[7] = (__bf16)(b.w * s);
    return v;
}

// ---------------- fused prepass (unchanged from v11) ----------------
// K: fp32 -> bf16 with slot^=key&15 baked. V: key-PERMUTED bf16 Vt so QK C-registers
// are directly the PV A-fragment (no repack shuffles in the main loop).
__global__ __launch_bounds__(256)
void prep_kv(const float* __restrict__ K, const float* __restrict__ V,
             unsigned char* __restrict__ kws, unsigned char* __restrict__ vtws) {
    const int blk = blockIdx.x, tid = threadIdx.x;

#pragma unroll
    for (int it = 0; it < 4; ++it) {
        int chunk = blk * 1024 + it * 256 + tid;   // 0 .. 1048575 (16B chunks)
        int c   = chunk & 15;
        int row = chunk >> 4;                      // bh*2048 + key
        int key = row & (SEQ - 1);
        const float* s = K + (long long)row * DDIM + c * 8;
        float4 a = *(const float4*)s;
        float4 b = *(const float4*)(s + 4);
        int c2 = c ^ (key & 15);                   // == swzK on tile byte key_local*256 + c*16
        *(bf16x8*)(kws + (long long)row * 256 + c2 * 16) = cvt8s(a, b, 1.0f);
    }

    __shared__ float vt[64][129];
    const int kt64 = blk & 31, bh = blk >> 5;
#pragma unroll
    for (int it = 0; it < 4; ++it) {
        int chunk = tid + it * 256;                // 0..1023
        int key = chunk >> 4, c = chunk & 15;
        const float* s = V + ((long long)(bh * SEQ + kt64 * 64 + key)) * DDIM + c * 8;
        float4 a = *(const float4*)s;
        float4 b = *(const float4*)(s + 4);
        vt[key][c * 8 + 0] = a.x; vt[key][c * 8 + 1] = a.y;
        vt[key][c * 8 + 2] = a.z; vt[key][c * 8 + 3] = a.w;
        vt[key][c * 8 + 4] = b.x; vt[key][c * 8 + 5] = b.y;
        vt[key][c * 8 + 6] = b.z; vt[key][c * 8 + 7] = b.w;
    }
    __syncthreads();
    int d = tid >> 1, half = tid & 1;              // d 0..127; keys half*32 .. half*32+31
#pragma unroll
    for (int ch = 0; ch < 4; ++ch) {
#pragma unroll
        for (int t = 0; t < 2; ++t) {
            int g  = half * 8 + ch * 2 + t;        // 4-key group: keys 4g..4g+3
            int b  = g >> 3, gb = g & 7;
            int hi = gb & 1, r2 = gb >> 1;
            int vcol = 32 * b + hi * 8 + (r2 & 1) * 4 + (r2 >> 1) * 16;
            unsigned int lo = (unsigned)bfb(vt[g * 4 + 0][d]) | ((unsigned)bfb(vt[g * 4 + 1][d]) << 16);
            unsigned int h2 = (unsigned)bfb(vt[g * 4 + 2][d]) | ((unsigned)bfb(vt[g * 4 + 3][d]) << 16);
            uint2 u; u.x = lo; u.y = h2;
            *(uint2*)(vtws + ((long long)(bh * 128 + d)) * 4096 + kt64 * 128 + vcol * 2) = u;
        }
    }
}

// ---- main: 64 q/wave (2 q-groups), QTILE=256, 1 block/CU — each K/V b128 feeds 2 MFMAs ----

__global__ __launch_bounds__(256, 1)
void attn_v12(const float* __restrict__ Q, const unsigned char* __restrict__ kws,
              const unsigned char* __restrict__ vtws, float* __restrict__ Out) {
    __shared__ __align__(16) unsigned char lds[2][32768];   // per buf: Ks 16K | Vt 16K

    const int tid = threadIdx.x;
    const int lane = tid & 63;
    const int w = tid >> 6;                                 // 0..3
    const int l31 = lane & 31, hi = lane >> 5;

    // bijective XCD swizzle: 256 blocks -> 32-block chunks per XCD (4 bh each, K+V 4MB = L2)
    const int bid = blockIdx.x;
    const int swz = ((bid & 7) << 5) | (bid >> 3);
    const int qt = swz & 7;
    const int bh = swz >> 3;

    const unsigned char* kbh = kws + (long long)bh * 524288;
    const unsigned char* vbh = vtws + (long long)bh * 524288;

    // ---- Q frags (B operand): q = qt*256 + w*64 + qg*32 + l31; d = ks*16 + hi*8 + j ----
    bf16x8 qf[2][8];
    const float* Qb = Q + ((long long)bh * SEQ + qt * 256 + w * 64 + l31) * DDIM;
#pragma unroll
    for (int qg = 0; qg < 2; ++qg)
#pragma unroll
        for (int ks = 0; ks < 8; ++ks) {
            const float* qp = Qb + qg * 32 * DDIM + ks * 16 + hi * 8;
            qf[qg][ks] = cvt8s(*(const float4*)qp, *(const float4*)(qp + 4), QSCALE);
        }

    f32x16 o[2][4];
#pragma unroll
    for (int qg = 0; qg < 2; ++qg)
#pragma unroll
        for (int db = 0; db < 4; ++db)
#pragma unroll
            for (int r = 0; r < 16; ++r) o[qg][db][r] = 0.f;
    float l_r[2] = { 0.f, 0.f };

    auto stage = [&](int buf, int kt) {
        unsigned char* Ksb = &lds[buf][0];
        unsigned char* Vtb = &lds[buf][16384];
#pragma unroll
        for (int i = 0; i < 4; ++i) {
            int sg = i * 256 + tid;                          // 0..1023
            gload16(kbh + kt * 16384 + sg * 16, Ksb + sg * 16);  // linear (swz baked in prep)
        }
#pragma unroll
        for (int i = 0; i < 4; ++i) {
            int sg = i * 256 + tid;                          // d = sg>>3, slot = sg&7
            int d = sg >> 3, s = sg & 7;
            gload16(vbh + d * 4096 + kt * 128 + ((s ^ (d & 7)) << 4), Vtb + sg * 16);
        }
    };

    stage(0, 0);
    __syncthreads();
    int cur = 0;

#pragma unroll 1
    for (int kt = 0; kt < NT; ++kt) {
        if (kt + 1 < NT) stage(cur ^ 1, kt + 1);

        unsigned char* Ksb = &lds[cur][0];
        unsigned char* Vtb = &lds[cur][16384];

        // ---- QK^T: sc[qg][kh]; each kf read feeds BOTH q-groups ----
        f32x16 sc00, sc01, sc10, sc11;   // sc[qg][kh]
#pragma unroll
        for (int r = 0; r < 16; ++r) { sc00[r]=0.f; sc01[r]=0.f; sc10[r]=0.f; sc11[r]=0.f; }
        __builtin_amdgcn_s_setprio(1);
#pragma unroll
        for (int ks = 0; ks < 8; ++ks) {
            bf16x8 kf0 = *(const bf16x8*)(Ksb + swzK((0 * 32 + l31) * 256 + ks * 32 + hi * 16));
            bf16x8 kf1 = *(const bf16x8*)(Ksb + swzK((1 * 32 + l31) * 256 + ks * 32 + hi * 16));
            sc00 = __builtin_amdgcn_mfma_f32_32x32x16_bf16(kf0, qf[0][ks], sc00, 0, 0, 0);
            sc10 = __builtin_amdgcn_mfma_f32_32x32x16_bf16(kf0, qf[1][ks], sc10, 0, 0, 0);
            sc01 = __builtin_amdgcn_mfma_f32_32x32x16_bf16(kf1, qf[0][ks], sc01, 0, 0, 0);
            sc11 = __builtin_amdgcn_mfma_f32_32x32x16_bf16(kf1, qf[1][ks], sc11, 0, 0, 0);
        }
        __builtin_amdgcn_s_setprio(0);

        // ================= phase A: keys 0-31 (V slices 0,1) =================
        bf16x8 vbrA[8];
#pragma unroll
        for (int ksv = 0; ksv < 2; ++ksv)
#pragma unroll
            for (int db = 0; db < 4; ++db) {
                int d = db * 32 + l31;
                vbrA[ksv * 4 + db] = *(const bf16x8*)(Vtb + swzV(d * 128 + ksv * 32 + hi * 16));
            }

        bf16x8 paA[2][2];
#pragma unroll
        for (int qg = 0; qg < 2; ++qg) {
            const f32x16& sc = qg ? sc10 : sc00;
            float p[16];
#pragma unroll
            for (int r = 0; r < 16; ++r) p[r] = __builtin_amdgcn_exp2f(sc[r]);
            float t8[8];
#pragma unroll
            for (int i = 0; i < 8; ++i) t8[i] = p[i] + p[i + 8];
#pragma unroll
            for (int st = 4; st >= 1; st >>= 1)
#pragma unroll
                for (int i = 0; i < st; ++i) t8[i] = t8[i] + t8[i + st];
            l_r[qg] += t8[0];
            unsigned int w0[4], w1[4];
#pragma unroll
            for (int t = 0; t < 4; ++t) {
                w0[t] = (unsigned)bfb(p[2 * t])     | ((unsigned)bfb(p[2 * t + 1]) << 16);
                w1[t] = (unsigned)bfb(p[8 + 2 * t]) | ((unsigned)bfb(p[8 + 2 * t + 1]) << 16);
            }
            paA[qg][0] = *(bf16x8*)w0;
            paA[qg][1] = *(bf16x8*)w1;
        }

        __builtin_amdgcn_s_setprio(1);
#pragma unroll
        for (int sl = 0; sl < 2; ++sl)
#pragma unroll
            for (int db = 0; db < 4; ++db) {
                o[0][db] = __builtin_amdgcn_mfma_f32_32x32x16_bf16(paA[0][sl], vbrA[sl * 4 + db], o[0][db], 0, 0, 0);
                o[1][db] = __builtin_amdgcn_mfma_f32_32x32x16_bf16(paA[1][sl], vbrA[sl * 4 + db], o[1][db], 0, 0, 0);
            }
        __builtin_amdgcn_s_setprio(0);

        // ================= phase B: keys 32-63 (V slices 2,3) =================
        bf16x8 vbrB[8];
#pragma unroll
        for (int ksv = 0; ksv < 2; ++ksv)
#pragma unroll
            for (int db = 0; db < 4; ++db) {
                int d = db * 32 + l31;
                vbrB[ksv * 4 + db] = *(const bf16x8*)(Vtb + swzV(d * 128 + (2 + ksv) * 32 + hi * 16));
            }

        bf16x8 paB[2][2];
#pragma unroll
        for (int qg = 0; qg < 2; ++qg) {
            const f32x16& sc = qg ? sc11 : sc01;
            float p[16];
#pragma unroll
            for (int r = 0; r < 16; ++r) p[r] = __builtin_amdgcn_exp2f(sc[r]);
            float t8[8];
#pragma unroll
            for (int i = 0; i < 8; ++i) t8[i] = p[i] + p[i + 8];
#pragma unroll
            for (int st = 4; st >= 1; st >>= 1)
#pragma unroll
                for (int i = 0; i < st; ++i) t8[i] = t8[i] + t8[i + st];
            l_r[qg] += t8[0];
            unsigned int w0[4], w1[4];
#pragma unroll
            for (int t = 0; t < 4; ++t) {
                w0[t] = (unsigned)bfb(p[2 * t])     | ((unsigned)bfb(p[2 * t + 1]) << 16);
                w1[t] = (unsigned)bfb(p[8 + 2 * t]) | ((unsigned)bfb(p[8 + 2 * t + 1]) << 16);
            }
            paB[qg][0] = *(bf16x8*)w0;
            paB[qg][1] = *(bf16x8*)w1;
        }

        __builtin_amdgcn_s_setprio(1);
#pragma unroll
        for (int sl = 0; sl < 2; ++sl)
#pragma unroll
            for (int db = 0; db < 4; ++db) {
                o[0][db] = __builtin_amdgcn_mfma_f32_32x32x16_bf16(paB[0][sl], vbrB[sl * 4 + db], o[0][db], 0, 0, 0);
                o[1][db] = __builtin_amdgcn_mfma_f32_32x32x16_bf16(paB[1][sl], vbrB[sl * 4 + db], o[1][db], 0, 0, 0);
            }
        __builtin_amdgcn_s_setprio(0);

        __syncthreads();
        cur ^= 1;
    }

    // ---- epilogue: per q-group cross-half l reduce, inv broadcast, store ----
    float* Ob = Out + ((long long)bh * SEQ + qt * 256 + w * 64) * DDIM;
#pragma unroll
    for (int qg = 0; qg < 2; ++qg) {
        float l = l_r[qg];
        l += __shfl_xor(l, 32);
        float inv = 1.0f / l;
        float invr[16];
#pragma unroll
        for (int r = 0; r < 16; ++r) invr[r] = __shfl(inv, (r & 3) + 8 * (r >> 2) + 4 * hi);
#pragma unroll
        for (int db = 0; db < 4; ++db)
#pragma unroll
            for (int r = 0; r < 16; ++r) {
                int row = qg * 32 + (r & 3) + 8 * (r >> 2) + 4 * hi;
                Ob[row * DDIM + db * 32 + l31] = o[qg][db][r] * invr[r];
            }
    }
}

// ---------------- fallback (used only if ws_size too small) ----------------

__device__ __forceinline__ int swz9(int b) { return b ^ (((b >> 9) & 7) << 4); }
__device__ __forceinline__ int swz8f(int b) { return b ^ (((b >> 8) & 7) << 4); }

__global__ __launch_bounds__(256, 4)
void attn_fwd_v1(const float* __restrict__ Q, const float* __restrict__ K,
                 const float* __restrict__ V, float* __restrict__ Out) {
    __shared__ __align__(16) unsigned char lds[16384 + 16384 + 4 * 2048];
    unsigned char* KsB = lds;
    unsigned char* VtB = lds + 16384;
    const int tid = threadIdx.x;
    const int lane = tid & 63;
    const int w = tid >> 6;
    const int l15 = lane & 15;
    const int g = lane >> 4;
    const int qt = blockIdx.x;
    const int bh = blockIdx.y;
    const long long base = (long long)bh * SEQ * DDIM;
    const float* Qb = Q + base + (long long)(qt * 64 + w * 16) * DDIM;
    const float* Kb = K + base;
    const float* Vb = V + base;
    unsigned char* PB = lds + 32768 + w * 2048;
    bf16x8 qf[4];
#pragma unroll
    for (int ks = 0; ks < 4; ++ks) {
        const float* qp = Qb + l15 * DDIM + ks * 32 + g * 8;
        qf[ks] = cvt8s(*(const float4*)qp, *(const float4*)(qp + 4), QSCALE);
    }
    f32x4 o[8];
#pragma unroll
    for (int cb = 0; cb < 8; ++cb) { o[cb][0]=0.f; o[cb][1]=0.f; o[cb][2]=0.f; o[cb][3]=0.f; }
    float m_r[4] = { -INFINITY, -INFINITY, -INFINITY, -INFINITY };
    float l_r[4] = { 0.f, 0.f, 0.f, 0.f };
    for (int kt = 0; kt < SEQ / 64; ++kt) {
        __syncthreads();
#pragma unroll
        for (int it = 0; it < 4; ++it) {
            int chunk = tid + it * 256;
            int key = chunk >> 4;
            int dc = (chunk & 15) * 8;
            const float* kp = Kb + (long long)(kt * 64 + key) * DDIM + dc;
            *(bf16x8*)(KsB + swz9(key * 256 + dc * 2)) = cvt8s(*(const float4*)kp, *(const float4*)(kp + 4), 1.0f);
        }
#pragma unroll
        for (int it = 0; it < 8; ++it) {
            int task = w + it * 4;
            int kq = task >> 1;
            int dh = task & 1;
            int key = kq * 4 + g;
            int d0 = dh * 64 + l15 * 4;
            const float* vp = Vb + (long long)(kt * 64 + key) * DDIM + d0;
            float4 a = *(const float4*)vp;
            *(__bf16*)(VtB + swz8f((d0 + 0) * 128 + key * 2)) = (__bf16)a.x;
            *(__bf16*)(VtB + swz8f((d0 + 1) * 128 + key * 2)) = (__bf16)a.y;
            *(__bf16*)(VtB + swz8f((d0 + 2) * 128 + key * 2)) = (__bf16)a.z;
            *(__bf16*)(VtB + swz8f((d0 + 3) * 128 + key * 2)) = (__bf16)a.w;
        }
        __syncthreads();
        f32x4 sc[4];
#pragma unroll
        for (int c = 0; c < 4; ++c) {
            f32x4 acc; acc[0]=0.f; acc[1]=0.f; acc[2]=0.f; acc[3]=0.f;
#pragma unroll
            for (int ks = 0; ks < 4; ++ks) {
                bf16x8 bf = *(const bf16x8*)(KsB + swz9((c * 16 + l15) * 256 + (ks * 32 + g * 8) * 2));
                acc = __builtin_amdgcn_mfma_f32_16x16x32_bf16(qf[ks], bf, acc, 0, 0, 0);
            }
            sc[c] = acc;
        }
#pragma unroll
        for (int r = 0; r < 4; ++r) {
            float s0 = sc[0][r], s1 = sc[1][r], s2 = sc[2][r], s3 = sc[3][r];
            float mx = fmaxf(fmaxf(s0, s1), fmaxf(s2, s3));
            mx = fmaxf(mx, __shfl_xor(mx, 1));
            mx = fmaxf(mx, __shfl_xor(mx, 2));
            mx = fmaxf(mx, __shfl_xor(mx, 4));
            mx = fmaxf(mx, __shfl_xor(mx, 8));
            float mold = m_r[r];
            float mnew = fmaxf(mold, mx);
            float alpha = __builtin_amdgcn_exp2f(mold - mnew);
            float p0 = __builtin_amdgcn_exp2f(s0 - mnew);
            float p1 = __builtin_amdgcn_exp2f(s1 - mnew);
            float p2 = __builtin_amdgcn_exp2f(s2 - mnew);
            float p3 = __builtin_amdgcn_exp2f(s3 - mnew);
            float sum = (p0 + p1) + (p2 + p3);
            sum += __shfl_xor(sum, 1);
            sum += __shfl_xor(sum, 2);
            sum += __shfl_xor(sum, 4);
            sum += __shfl_xor(sum, 8);
            l_r[r] = l_r[r] * alpha + sum;
            m_r[r] = mnew;
#pragma unroll
            for (int cb = 0; cb < 8; ++cb) o[cb][r] *= alpha;
            int row = g * 4 + r;
            *(__bf16*)(PB + swz8f(row * 128 + (0 * 16 + l15) * 2)) = (__bf16)p0;
            *(__bf16*)(PB + swz8f(row * 128 + (1 * 16 + l15) * 2)) = (__bf16)p1;
            *(__bf16*)(PB + swz8f(row * 128 + (2 * 16 + l15) * 2)) = (__bf16)p2;
            *(__bf16*)(PB + swz8f(row * 128 + (3 * 16 + l15) * 2)) = (__bf16)p3;
        }
#pragma unroll
        for (int kk = 0; kk < 2; ++kk) {
            bf16x8 pa = *(const bf16x8*)(PB + swz8f(l15 * 128 + (kk * 32 + g * 8) * 2));
#pragma unroll
            for (int cb = 0; cb < 8; ++cb) {
                bf16x8 vb = *(const bf16x8*)(VtB + swz8f((cb * 16 + l15) * 128 + (kk * 32 + g * 8) * 2));
                o[cb] = __builtin_amdgcn_mfma_f32_16x16x32_bf16(pa, vb, o[cb], 0, 0, 0);
            }
        }
    }
    float* Ob = Out + base + (long long)(qt * 64 + w * 16) * DDIM;
#pragma unroll
    for (int r = 0; r < 4; ++r) {
        float inv = 1.0f / l_r[r];
        int row = g * 4 + r;
#pragma unroll
        for (int cb = 0; cb < 8; ++cb) Ob[row * DDIM + cb * 16 + l15] = o[cb][r] * inv;
    }
}

extern "C" void kernel_launch(void* const* d_in, const int* in_sizes, int n_in,
                              void* d_out, int out_size, void* d_ws, size_t ws_size,
                              hipStream_t stream) {
    const float* Q = (const float*)d_in[0];
    const float* K = (const float*)d_in[1];
    const float* V = (const float*)d_in[2];
    float* Out = (float*)d_out;

    if (ws_size >= (size_t)32 * 1024 * 1024) {
        unsigned char* ws = (unsigned char*)d_ws;
        unsigned char* kws = ws;
        unsigned char* vtws = ws + (size_t)16 * 1024 * 1024;
        prep_kv<<<1024, 256, 0, stream>>>(K, V, kws, vtws);
        attn_v12<<<256, 256, 0, stream>>>(Q, kws, vtws, Out);
    } else {
        attn_fwd_v1<<<dim3(32, 32), 256, 0, stream>>>(Q, K, V, Out);
    }
}

// Round 13
// 96.939 us; speedup vs baseline: 1.0117x; 1.0117x over previous
//
#include <hip/hip_runtime.h>
#include <hip/hip_bf16.h>
#include <math.h>

#define SEQ   2048
#define DDIM  128
#define NBH   32
#define KVB   64
#define NT    (SEQ / KVB)        // 32 kv tiles
#define QSCALE (0.08838834764831845f * 1.4426950408889634f)  // 1/sqrt(128) * log2(e)

typedef __bf16 bf16x8 __attribute__((ext_vector_type(8)));
typedef float  f32x4  __attribute__((ext_vector_type(4)));
typedef float  f32x16 __attribute__((ext_vector_type(16)));
typedef unsigned short u16x8 __attribute__((ext_vector_type(8)));

// Ks tile: byte = key*256 + off. Read swizzle: 16B-slot ^= key&15 (baked in prep).
__device__ __forceinline__ int swzK(int b) { return b ^ (((b >> 8) & 15) << 4); }
// Vt tile: byte = d*128 + off. slot ^= d&7 (baked into stage source).
__device__ __forceinline__ int swzV(int b) { return b ^ (((b >> 7) & 7) << 4); }

__device__ __forceinline__ void gload16(const void* g, void* l) {
    __builtin_amdgcn_global_load_lds(
        (const __attribute__((address_space(1))) unsigned int*)g,
        (__attribute__((address_space(3))) unsigned int*)l, 16, 0, 0);
}
__device__ __forceinline__ unsigned short bfb(float x) {
    return __builtin_bit_cast(unsigned short, (__bf16)x);
}
__device__ __forceinline__ bf16x8 cvt8s(float4 a, float4 b, float s) {
    bf16x8 v;
    v[0] = (__bf16)(a.x * s); v[1] = (__bf16)(a.y * s);
    v[2] = (__bf16)(a.z * s); v[3] = (__bf16)(a.w * s);
    v[4] = (__bf16)(b.x * s); v[5] = (__bf16)(b.y * s);
    v[6] = (__bf16)(b.z * s); v[7] = (__bf16)(b.w * s);
    return v;
}

// ---------------- fused prepass ----------------
// K: fp32 -> bf16 with slot^=key&15 baked. V: key-PERMUTED bf16 Vt so QK C-registers
// are directly the PV A-fragment. V stores now COALESCED: each thread assembles one
// 16B slot of a row-strip via the inverse permutation; lanes 0-7 cover 128B contiguous.
__global__ __launch_bounds__(256)
void prep_kv(const float* __restrict__ K, const float* __restrict__ V,
             unsigned char* __restrict__ kws, unsigned char* __restrict__ vtws) {
    const int blk = blockIdx.x, tid = threadIdx.x;

#pragma unroll
    for (int it = 0; it < 4; ++it) {
        int chunk = blk * 1024 + it * 256 + tid;   // 0 .. 1048575 (16B chunks)
        int c   = chunk & 15;
        int row = chunk >> 4;                      // bh*2048 + key
        int key = row & (SEQ - 1);
        const float* s = K + (long long)row * DDIM + c * 8;
        float4 a = *(const float4*)s;
        float4 b = *(const float4*)(s + 4);
        int c2 = c ^ (key & 15);                   // == swzK on tile byte key_local*256 + c*16
        *(bf16x8*)(kws + (long long)row * 256 + c2 * 16) = cvt8s(a, b, 1.0f);
    }

    __shared__ float vt[64][129];
    const int kt64 = blk & 31, bh = blk >> 5;
#pragma unroll
    for (int it = 0; it < 4; ++it) {
        int chunk = tid + it * 256;                // 0..1023
        int key = chunk >> 4, c = chunk & 15;
        const float* s = V + ((long long)(bh * SEQ + kt64 * 64 + key)) * DDIM + c * 8;
        float4 a = *(const float4*)s;
        float4 b = *(const float4*)(s + 4);
        vt[key][c * 8 + 0] = a.x; vt[key][c * 8 + 1] = a.y;
        vt[key][c * 8 + 2] = a.z; vt[key][c * 8 + 3] = a.w;
        vt[key][c * 8 + 4] = b.x; vt[key][c * 8 + 5] = b.y;
        vt[key][c * 8 + 6] = b.z; vt[key][c * 8 + 7] = b.w;
    }
    __syncthreads();
    // coalesced permuted stores: (d, slot) pairs; inverse perm: vcol v -> key
    //   key = (v&32) + 16*((v>>4)&1) + 8*((v>>2)&1) + 4*((v>>3)&1) + (v&3)
    // (verified against forward map: k=4->v8, k=8->v4, k=16->v16, k=20->v24, k=33->v33)
#pragma unroll
    for (int it = 0; it < 4; ++it) {
        int pair = it * 256 + tid;                 // 0..1023
        int d = pair >> 3, sl = pair & 7;
        u16x8 u;
#pragma unroll
        for (int j = 0; j < 8; ++j) {
            int v = sl * 8 + j;
            int key = (v & 32) + (((v >> 4) & 1) << 4) + (((v >> 2) & 1) << 3)
                    + (((v >> 3) & 1) << 2) + (v & 3);
            u[j] = bfb(vt[key][d]);
        }
        *(u16x8*)(vtws + ((long long)(bh * 128 + d)) * 4096 + kt64 * 128 + sl * 16) = u;
    }
}

// ---- main: v11 structure + zero-C seed + 4 QK chains (halved dep depth) ----

__global__ __launch_bounds__(256, 2)
void attn_v13(const float* __restrict__ Q, const unsigned char* __restrict__ kws,
              const unsigned char* __restrict__ vtws, float* __restrict__ Out) {
    __shared__ __align__(16) unsigned char lds[2][32768];   // per buf: Ks 16K | Vt 16K

    const int tid = threadIdx.x;
    const int lane = tid & 63;
    const int w = tid >> 6;                                 // 0..3
    const int l31 = lane & 31, hi = lane >> 5;

    // bijective XCD swizzle: 512 blocks -> 64-block chunks per XCD (4 bh each)
    const int bid = blockIdx.x;
    const int swz = ((bid & 7) << 6) | (bid >> 3);
    const int qt = swz & 15;
    const int bh = swz >> 4;

    const unsigned char* kbh = kws + (long long)bh * 524288;
    const unsigned char* vbh = vtws + (long long)bh * 524288;

    // ---- Q frags (B operand of QK): q = qt*128 + w*32 + l31; k-slice d = ks*16 + hi*8 + j ----
    bf16x8 qf[8];
    const float* Qb = Q + ((long long)bh * SEQ + qt * 128 + w * 32 + l31) * DDIM;
#pragma unroll
    for (int ks = 0; ks < 8; ++ks) {
        const float* qp = Qb + ks * 16 + hi * 8;
        qf[ks] = cvt8s(*(const float4*)qp, *(const float4*)(qp + 4), QSCALE);
    }

    f32x16 o[4];
#pragma unroll
    for (int db = 0; db < 4; ++db)
#pragma unroll
        for (int r = 0; r < 16; ++r) o[db][r] = 0.f;
    float l_r = 0.f;   // per-lane partial sum of exp2(score); cross-half reduce at end

    f32x16 zf;         // persistent zero C-operand: chains seed from this (no per-kt re-zero)
#pragma unroll
    for (int r = 0; r < 16; ++r) zf[r] = 0.f;

    auto stage = [&](int buf, int kt) {
        unsigned char* Ksb = &lds[buf][0];
        unsigned char* Vtb = &lds[buf][16384];
#pragma unroll
        for (int i = 0; i < 4; ++i) {
            int sg = i * 256 + tid;                          // 0..1023
            gload16(kbh + kt * 16384 + sg * 16, Ksb + sg * 16);  // linear (swz baked in prep)
        }
#pragma unroll
        for (int i = 0; i < 4; ++i) {
            int sg = i * 256 + tid;                          // d = sg>>3, slot = sg&7
            int d = sg >> 3, s = sg & 7;
            gload16(vbh + d * 4096 + kt * 128 + ((s ^ (d & 7)) << 4), Vtb + sg * 16);
        }
    };

    stage(0, 0);
    __syncthreads();
    int cur = 0;

#pragma unroll 1
    for (int kt = 0; kt < NT; ++kt) {
        if (kt + 1 < NT) stage(cur ^ 1, kt + 1);

        unsigned char* Ksb = &lds[cur][0];
        unsigned char* Vtb = &lds[cur][16384];

        // ---- QK^T: 4 independent chains of depth 4 (ks-halves), seeded from zf ----
        f32x16 s0a, s0b, s1a, s1b;
        __builtin_amdgcn_s_setprio(1);
#pragma unroll
        for (int ks = 0; ks < 8; ++ks) {
            bf16x8 kf0 = *(const bf16x8*)(Ksb + swzK((0 * 32 + l31) * 256 + ks * 32 + hi * 16));
            bf16x8 kf1 = *(const bf16x8*)(Ksb + swzK((1 * 32 + l31) * 256 + ks * 32 + hi * 16));
            if (ks == 0) {
                s0a = __builtin_amdgcn_mfma_f32_32x32x16_bf16(kf0, qf[0], zf, 0, 0, 0);
                s1a = __builtin_amdgcn_mfma_f32_32x32x16_bf16(kf1, qf[0], zf, 0, 0, 0);
            } else if (ks < 4) {
                s0a = __builtin_amdgcn_mfma_f32_32x32x16_bf16(kf0, qf[ks], s0a, 0, 0, 0);
                s1a = __builtin_amdgcn_mfma_f32_32x32x16_bf16(kf1, qf[ks], s1a, 0, 0, 0);
            } else if (ks == 4) {
                s0b = __builtin_amdgcn_mfma_f32_32x32x16_bf16(kf0, qf[4], zf, 0, 0, 0);
                s1b = __builtin_amdgcn_mfma_f32_32x32x16_bf16(kf1, qf[4], zf, 0, 0, 0);
            } else {
                s0b = __builtin_amdgcn_mfma_f32_32x32x16_bf16(kf0, qf[ks], s0b, 0, 0, 0);
                s1b = __builtin_amdgcn_mfma_f32_32x32x16_bf16(kf1, qf[ks], s1b, 0, 0, 0);
            }
        }
        __builtin_amdgcn_s_setprio(0);
        f32x16 sc0 = s0a + s0b;
        f32x16 sc1 = s1a + s1b;

        // ================= phase A: keys 0-31 (V slices 0,1) =================
        bf16x8 vbrA[8];
#pragma unroll
        for (int ksv = 0; ksv < 2; ++ksv)
#pragma unroll
            for (int db = 0; db < 4; ++db) {
                int d = db * 32 + l31;
                vbrA[ksv * 4 + db] = *(const bf16x8*)(Vtb + swzV(d * 128 + ksv * 32 + hi * 16));
            }

        float pA[16];
#pragma unroll
        for (int r = 0; r < 16; ++r) pA[r] = __builtin_amdgcn_exp2f(sc0[r]);
        float tA[8];
#pragma unroll
        for (int i = 0; i < 8; ++i) tA[i] = pA[i] + pA[i + 8];
#pragma unroll
        for (int st = 4; st >= 1; st >>= 1)
#pragma unroll
            for (int i = 0; i < st; ++i) tA[i] = tA[i] + tA[i + st];
        float sumA = tA[0];

        unsigned int t0w[4], t1w[4];
#pragma unroll
        for (int t = 0; t < 4; ++t) {
            t0w[t] = (unsigned)bfb(pA[2 * t])     | ((unsigned)bfb(pA[2 * t + 1]) << 16);
            t1w[t] = (unsigned)bfb(pA[8 + 2 * t]) | ((unsigned)bfb(pA[8 + 2 * t + 1]) << 16);
        }
        bf16x8 pa0 = *(bf16x8*)t0w;
        bf16x8 pa1 = *(bf16x8*)t1w;

        __builtin_amdgcn_s_setprio(1);
#pragma unroll
        for (int db = 0; db < 4; ++db)
            o[db] = __builtin_amdgcn_mfma_f32_32x32x16_bf16(pa0, vbrA[0 * 4 + db], o[db], 0, 0, 0);
#pragma unroll
        for (int db = 0; db < 4; ++db)
            o[db] = __builtin_amdgcn_mfma_f32_32x32x16_bf16(pa1, vbrA[1 * 4 + db], o[db], 0, 0, 0);
        __builtin_amdgcn_s_setprio(0);

        // ================= phase B: keys 32-63 (V slices 2,3) =================
        bf16x8 vbrB[8];
#pragma unroll
        for (int ksv = 0; ksv < 2; ++ksv)
#pragma unroll
            for (int db = 0; db < 4; ++db) {
                int d = db * 32 + l31;
                vbrB[ksv * 4 + db] = *(const bf16x8*)(Vtb + swzV(d * 128 + (2 + ksv) * 32 + hi * 16));
            }

        float pB[16];
#pragma unroll
        for (int r = 0; r < 16; ++r) pB[r] = __builtin_amdgcn_exp2f(sc1[r]);
        float tB[8];
#pragma unroll
        for (int i = 0; i < 8; ++i) tB[i] = pB[i] + pB[i + 8];
#pragma unroll
        for (int st = 4; st >= 1; st >>= 1)
#pragma unroll
            for (int i = 0; i < st; ++i) tB[i] = tB[i] + tB[i + st];
        l_r += sumA + tB[0];

        unsigned int t2w[4], t3w[4];
#pragma unroll
        for (int t = 0; t < 4; ++t) {
            t2w[t] = (unsigned)bfb(pB[2 * t])     | ((unsigned)bfb(pB[2 * t + 1]) << 16);
            t3w[t] = (unsigned)bfb(pB[8 + 2 * t]) | ((unsigned)bfb(pB[8 + 2 * t + 1]) << 16);
        }
        bf16x8 pa2 = *(bf16x8*)t2w;
        bf16x8 pa3 = *(bf16x8*)t3w;

        __builtin_amdgcn_s_setprio(1);
#pragma unroll
        for (int db = 0; db < 4; ++db)
            o[db] = __builtin_amdgcn_mfma_f32_32x32x16_bf16(pa2, vbrB[0 * 4 + db], o[db], 0, 0, 0);
#pragma unroll
        for (int db = 0; db < 4; ++db)
            o[db] = __builtin_amdgcn_mfma_f32_32x32x16_bf16(pa3, vbrB[1 * 4 + db], o[db], 0, 0, 0);
        __builtin_amdgcn_s_setprio(0);

        __syncthreads();
        cur ^= 1;
    }

    // ---- epilogue: cross-half l reduce, per-row inv broadcast, store ----
    l_r += __shfl_xor(l_r, 32);
    float inv = 1.0f / l_r;
    float invr[16];
#pragma unroll
    for (int r = 0; r < 16; ++r) invr[r] = __shfl(inv, (r & 3) + 8 * (r >> 2) + 4 * hi);
    float* Ob = Out + ((long long)bh * SEQ + qt * 128 + w * 32) * DDIM;
#pragma unroll
    for (int db = 0; db < 4; ++db)
#pragma unroll
        for (int r = 0; r < 16; ++r) {
            int row = (r & 3) + 8 * (r >> 2) + 4 * hi;
            Ob[row * DDIM + db * 32 + l31] = o[db][r] * invr[r];
        }
}

// ---------------- fallback (used only if ws_size too small) ----------------

__device__ __forceinline__ int swz9(int b) { return b ^ (((b >> 9) & 7) << 4); }
__device__ __forceinline__ int swz8f(int b) { return b ^ (((b >> 8) & 7) << 4); }

__global__ __launch_bounds__(256, 4)
void attn_fwd_v1(const float* __restrict__ Q, const float* __restrict__ K,
                 const float* __restrict__ V, float* __restrict__ Out) {
    __shared__ __align__(16) unsigned char lds[16384 + 16384 + 4 * 2048];
    unsigned char* KsB = lds;
    unsigned char* VtB = lds + 16384;
    const int tid = threadIdx.x;
    const int lane = tid & 63;
    const int w = tid >> 6;
    const int l15 = lane & 15;
    const int g = lane >> 4;
    const int qt = blockIdx.x;
    const int bh = blockIdx.y;
    const long long base = (long long)bh * SEQ * DDIM;
    const float* Qb = Q + base + (long long)(qt * 64 + w * 16) * DDIM;
    const float* Kb = K + base;
    const float* Vb = V + base;
    unsigned char* PB = lds + 32768 + w * 2048;
    bf16x8 qf[4];
#pragma unroll
    for (int ks = 0; ks < 4; ++ks) {
        const float* qp = Qb + l15 * DDIM + ks * 32 + g * 8;
        qf[ks] = cvt8s(*(const float4*)qp, *(const float4*)(qp + 4), QSCALE);
    }
    f32x4 o[8];
#pragma unroll
    for (int cb = 0; cb < 8; ++cb) { o[cb][0]=0.f; o[cb][1]=0.f; o[cb][2]=0.f; o[cb][3]=0.f; }
    float m_r[4] = { -INFINITY, -INFINITY, -INFINITY, -INFINITY };
    float l_r[4] = { 0.f, 0.f, 0.f, 0.f };
    for (int kt = 0; kt < SEQ / 64; ++kt) {
        __syncthreads();
#pragma unroll
        for (int it = 0; it < 4; ++it) {
            int chunk = tid + it * 256;
            int key = chunk >> 4;
            int dc = (chunk & 15) * 8;
            const float* kp = Kb + (long long)(kt * 64 + key) * DDIM + dc;
            *(bf16x8*)(KsB + swz9(key * 256 + dc * 2)) = cvt8s(*(const float4*)kp, *(const float4*)(kp + 4), 1.0f);
        }
#pragma unroll
        for (int it = 0; it < 8; ++it) {
            int task = w + it * 4;
            int kq = task >> 1;
            int dh = task & 1;
            int key = kq * 4 + g;
            int d0 = dh * 64 + l15 * 4;
            const float* vp = Vb + (long long)(kt * 64 + key) * DDIM + d0;
            float4 a = *(const float4*)vp;
            *(__bf16*)(VtB + swz8f((d0 + 0) * 128 + key * 2)) = (__bf16)a.x;
            *(__bf16*)(VtB + swz8f((d0 + 1) * 128 + key * 2)) = (__bf16)a.y;
            *(__bf16*)(VtB + swz8f((d0 + 2) * 128 + key * 2)) = (__bf16)a.z;
            *(__bf16*)(VtB + swz8f((d0 + 3) * 128 + key * 2)) = (__bf16)a.w;
        }
        __syncthreads();
        f32x4 sc[4];
#pragma unroll
        for (int c = 0; c < 4; ++c) {
            f32x4 acc; acc[0]=0.f; acc[1]=0.f; acc[2]=0.f; acc[3]=0.f;
#pragma unroll
            for (int ks = 0; ks < 4; ++ks) {
                bf16x8 bf = *(const bf16x8*)(KsB + swz9((c * 16 + l15) * 256 + (ks * 32 + g * 8) * 2));
                acc = __builtin_amdgcn_mfma_f32_16x16x32_bf16(qf[ks], bf, acc, 0, 0, 0);
            }
            sc[c] = acc;
        }
#pragma unroll
        for (int r = 0; r < 4; ++r) {
            float s0 = sc[0][r], s1 = sc[1][r], s2 = sc[2][r], s3 = sc[3][r];
            float mx = fmaxf(fmaxf(s0, s1), fmaxf(s2, s3));
            mx = fmaxf(mx, __shfl_xor(mx, 1));
            mx = fmaxf(mx, __shfl_xor(mx, 2));
            mx = fmaxf(mx, __shfl_xor(mx, 4));
            mx = fmaxf(mx, __shfl_xor(mx, 8));
            float mold = m_r[r];
            float mnew = fmaxf(mold, mx);
            float alpha = __builtin_amdgcn_exp2f(mold - mnew);
            float p0 = __builtin_amdgcn_exp2f(s0 - mnew);
            float p1 = __builtin_amdgcn_exp2f(s1 - mnew);
            float p2 = __builtin_amdgcn_exp2f(s2 - mnew);
            float p3 = __builtin_amdgcn_exp2f(s3 - mnew);
            float sum = (p0 + p1) + (p2 + p3);
            sum += __shfl_xor(sum, 1);
            sum += __shfl_xor(sum, 2);
            sum += __shfl_xor(sum, 4);
            sum += __shfl_xor(sum, 8);
            l_r[r] = l_r[r] * alpha + sum;
            m_r[r] = mnew;
#pragma unroll
            for (int cb = 0; cb < 8; ++cb) o[cb][r] *= alpha;
            int row = g * 4 + r;
            *(__bf16*)(PB + swz8f(row * 128 + (0 * 16 + l15) * 2)) = (__bf16)p0;
            *(__bf16*)(PB + swz8f(row * 128 + (1 * 16 + l15) * 2)) = (__bf16)p1;
            *(__bf16*)(PB + swz8f(row * 128 + (2 * 16 + l15) * 2)) = (__bf16)p2;
            *(__bf16*)(PB + swz8f(row * 128 + (3 * 16 + l15) * 2)) = (__bf16)p3;
        }
#pragma unroll
        for (int kk = 0; kk < 2; ++kk) {
            bf16x8 pa = *(const bf16x8*)(PB + swz8f(l15 * 128 + (kk * 32 + g * 8) * 2));
#pragma unroll
            for (int cb = 0; cb < 8; ++cb) {
                bf16x8 vb = *(const bf16x8*)(VtB + swz8f((cb * 16 + l15) * 128 + (kk * 32 + g * 8) * 2));
                o[cb] = __builtin_amdgcn_mfma_f32_16x16x32_bf16(pa, vb, o[cb], 0, 0, 0);
            }
        }
    }
    float* Ob = Out + base + (long long)(qt * 64 + w * 16) * DDIM;
#pragma unroll
    for (int r = 0; r < 4; ++r) {
        float inv = 1.0f / l_r[r];
        int row = g * 4 + r;
#pragma unroll
        for (int cb = 0; cb < 8; ++cb) Ob[row * DDIM + cb * 16 + l15] = o[cb][r] * inv;
    }
}

extern "C" void kernel_launch(void* const* d_in, const int* in_sizes, int n_in,
                              void* d_out, int out_size, void* d_ws, size_t ws_size,
                              hipStream_t stream) {
    const float* Q = (const float*)d_in[0];
    const float* K = (const float*)d_in[1];
    const float* V = (const float*)d_in[2];
    float* Out = (float*)d_out;

    if (ws_size >= (size_t)32 * 1024 * 1024) {
        unsigned char* ws = (unsigned char*)d_ws;
        unsigned char* kws = ws;
        unsigned char* vtws = ws + (size_t)16 * 1024 * 1024;
        prep_kv<<<1024, 256, 0, stream>>>(K, V, kws, vtws);
        attn_v13<<<512, 256, 0, stream>>>(Q, kws, vtws, Out);
    } else {
        attn_fwd_v1<<<dim3(32, 32), 256, 0, stream>>>(Q, K, V, Out);
    }
}

// Round 14
// 94.764 us; speedup vs baseline: 1.0349x; 1.0230x over previous
//
#include <hip/hip_runtime.h>
#include <hip/hip_bf16.h>
#include <math.h>

#define SEQ   2048
#define DDIM  128
#define NBH   32
#define KVB   64
#define NT    (SEQ / KVB)        // 32 kv tiles
#define QSCALE (0.08838834764831845f * 1.4426950408889634f)  // 1/sqrt(128) * log2(e)

typedef __bf16 bf16x8 __attribute__((ext_vector_type(8)));
typedef float  f32x4  __attribute__((ext_vector_type(4)));
typedef float  f32x16 __attribute__((ext_vector_type(16)));
typedef unsigned short u16x8 __attribute__((ext_vector_type(8)));

// Ks tile: byte = key*256 + off. Read swizzle: 16B-slot ^= key&15 (baked in prep).
__device__ __forceinline__ int swzK(int b) { return b ^ (((b >> 8) & 15) << 4); }
// Vt tile: byte = d*128 + off. slot ^= d&7 (baked into stage source).
__device__ __forceinline__ int swzV(int b) { return b ^ (((b >> 7) & 7) << 4); }

__device__ __forceinline__ void gload16(const void* g, void* l) {
    __builtin_amdgcn_global_load_lds(
        (const __attribute__((address_space(1))) unsigned int*)g,
        (__attribute__((address_space(3))) unsigned int*)l, 16, 0, 0);
}
__device__ __forceinline__ unsigned short bfb(float x) {
    return __builtin_bit_cast(unsigned short, (__bf16)x);
}
__device__ __forceinline__ bf16x8 cvt8s(float4 a, float4 b, float s) {
    bf16x8 v;
    v[0] = (__bf16)(a.x * s); v[1] = (__bf16)(a.y * s);
    v[2] = (__bf16)(a.z * s); v[3] = (__bf16)(a.w * s);
    v[4] = (__bf16)(b.x * s); v[5] = (__bf16)(b.y * s);
    v[6] = (__bf16)(b.z * s); v[7] = (__bf16)(b.w * s);
    return v;
}

// ---------------- fused prepass ----------------
// K: fp32 -> bf16 with slot^=key&15 baked. V: key-PERMUTED bf16 Vt so QK C-registers
// are directly the PV A-fragment (no repack shuffles in the main loop).
//    For within-tile key k: c=k&31, r1=c&3, hi=(c>>2)&1, r2=c>>3;
//    vcol = 32*(k>>5) + hi*8 + (r2&1)*4 + r1 + (r2>>1)*16.
__global__ __launch_bounds__(256)
void prep_kv(const float* __restrict__ K, const float* __restrict__ V,
             unsigned char* __restrict__ kws, unsigned char* __restrict__ vtws) {
    const int blk = blockIdx.x, tid = threadIdx.x;

#pragma unroll
    for (int it = 0; it < 4; ++it) {
        int chunk = blk * 1024 + it * 256 + tid;   // 0 .. 1048575 (16B chunks)
        int c   = chunk & 15;
        int row = chunk >> 4;                      // bh*2048 + key
        int key = row & (SEQ - 1);
        const float* s = K + (long long)row * DDIM + c * 8;
        float4 a = *(const float4*)s;
        float4 b = *(const float4*)(s + 4);
        int c2 = c ^ (key & 15);                   // == swzK on tile byte key_local*256 + c*16
        *(bf16x8*)(kws + (long long)row * 256 + c2 * 16) = cvt8s(a, b, 1.0f);
    }

    __shared__ float vt[64][129];
    const int kt64 = blk & 31, bh = blk >> 5;
#pragma unroll
    for (int it = 0; it < 4; ++it) {
        int chunk = tid + it * 256;                // 0..1023
        int key = chunk >> 4, c = chunk & 15;
        const float* s = V + ((long long)(bh * SEQ + kt64 * 64 + key)) * DDIM + c * 8;
        float4 a = *(const float4*)s;
        float4 b = *(const float4*)(s + 4);
        vt[key][c * 8 + 0] = a.x; vt[key][c * 8 + 1] = a.y;
        vt[key][c * 8 + 2] = a.z; vt[key][c * 8 + 3] = a.w;
        vt[key][c * 8 + 4] = b.x; vt[key][c * 8 + 5] = b.y;
        vt[key][c * 8 + 6] = b.z; vt[key][c * 8 + 7] = b.w;
    }
    __syncthreads();
    int d = tid >> 1, half = tid & 1;              // d 0..127; keys half*32 .. half*32+31
#pragma unroll
    for (int ch = 0; ch < 4; ++ch) {
#pragma unroll
        for (int t = 0; t < 2; ++t) {
            int g  = half * 8 + ch * 2 + t;        // 4-key group: keys 4g..4g+3
            int b  = g >> 3, gb = g & 7;
            int hi = gb & 1, r2 = gb >> 1;
            int vcol = 32 * b + hi * 8 + (r2 & 1) * 4 + (r2 >> 1) * 16;
            unsigned int lo = (unsigned)bfb(vt[g * 4 + 0][d]) | ((unsigned)bfb(vt[g * 4 + 1][d]) << 16);
            unsigned int h2 = (unsigned)bfb(vt[g * 4 + 2][d]) | ((unsigned)bfb(vt[g * 4 + 3][d]) << 16);
            uint2 u; u.x = lo; u.y = h2;
            *(uint2*)(vtws + ((long long)(bh * 128 + d)) * 4096 + kt64 * 128 + vcol * 2) = u;
        }
    }
}

// ---- main: v11 — 4-wave blocks, 32q/wave, 32x32x16 MFMA, no max-tracking,
//      key-permutation-baked free P->PV repack, dbuf gload_lds staging ----

__global__ __launch_bounds__(256, 2)
void attn_v11(const float* __restrict__ Q, const unsigned char* __restrict__ kws,
              const unsigned char* __restrict__ vtws, float* __restrict__ Out) {
    __shared__ __align__(16) unsigned char lds[2][32768];   // per buf: Ks 16K | Vt 16K

    const int tid = threadIdx.x;
    const int lane = tid & 63;
    const int w = tid >> 6;                                 // 0..3
    const int l31 = lane & 31, hi = lane >> 5;

    // bijective XCD swizzle: 512 blocks -> 64-block chunks per XCD (4 bh each)
    const int bid = blockIdx.x;
    const int swz = ((bid & 7) << 6) | (bid >> 3);
    const int qt = swz & 15;
    const int bh = swz >> 4;

    const unsigned char* kbh = kws + (long long)bh * 524288;
    const unsigned char* vbh = vtws + (long long)bh * 524288;

    // ---- Q frags (B operand of QK): q = qt*128 + w*32 + l31; k-slice d = ks*16 + hi*8 + j ----
    bf16x8 qf[8];
    const float* Qb = Q + ((long long)bh * SEQ + qt * 128 + w * 32 + l31) * DDIM;
#pragma unroll
    for (int ks = 0; ks < 8; ++ks) {
        const float* qp = Qb + ks * 16 + hi * 8;
        qf[ks] = cvt8s(*(const float4*)qp, *(const float4*)(qp + 4), QSCALE);
    }

    f32x16 o[4];
#pragma unroll
    for (int db = 0; db < 4; ++db)
#pragma unroll
        for (int r = 0; r < 16; ++r) o[db][r] = 0.f;
    float l_r = 0.f;   // per-lane partial sum of exp2(score); cross-half reduce at end

    auto stage = [&](int buf, int kt) {
        unsigned char* Ksb = &lds[buf][0];
        unsigned char* Vtb = &lds[buf][16384];
#pragma unroll
        for (int i = 0; i < 4; ++i) {
            int sg = i * 256 + tid;                          // 0..1023
            gload16(kbh + kt * 16384 + sg * 16, Ksb + sg * 16);  // linear (swz baked in prep)
        }
#pragma unroll
        for (int i = 0; i < 4; ++i) {
            int sg = i * 256 + tid;                          // d = sg>>3, slot = sg&7
            int d = sg >> 3, s = sg & 7;
            gload16(vbh + d * 4096 + kt * 128 + ((s ^ (d & 7)) << 4), Vtb + sg * 16);
        }
    };

    stage(0, 0);
    __syncthreads();
    int cur = 0;

#pragma unroll 1
    for (int kt = 0; kt < NT; ++kt) {
        if (kt + 1 < NT) stage(cur ^ 1, kt + 1);

        unsigned char* Ksb = &lds[cur][0];
        unsigned char* Vtb = &lds[cur][16384];

        // ---- QK^T both key-halves (32x32x16): lane q=l31; C-row=(reg&3)+8(reg>>2)+4hi ----
        f32x16 sc0, sc1;
#pragma unroll
        for (int r = 0; r < 16; ++r) { sc0[r] = 0.f; sc1[r] = 0.f; }
        __builtin_amdgcn_s_setprio(1);
#pragma unroll
        for (int ks = 0; ks < 8; ++ks) {
            bf16x8 kf0 = *(const bf16x8*)(Ksb + swzK((0 * 32 + l31) * 256 + ks * 32 + hi * 16));
            bf16x8 kf1 = *(const bf16x8*)(Ksb + swzK((1 * 32 + l31) * 256 + ks * 32 + hi * 16));
            sc0 = __builtin_amdgcn_mfma_f32_32x32x16_bf16(kf0, qf[ks], sc0, 0, 0, 0);
            sc1 = __builtin_amdgcn_mfma_f32_32x32x16_bf16(kf1, qf[ks], sc1, 0, 0, 0);
        }
        __builtin_amdgcn_s_setprio(0);

        // ================= phase A: keys 0-31 (V slices 0,1) =================
        bf16x8 vbrA[8];
#pragma unroll
        for (int ksv = 0; ksv < 2; ++ksv)
#pragma unroll
            for (int db = 0; db < 4; ++db) {
                int d = db * 32 + l31;
                vbrA[ksv * 4 + db] = *(const bf16x8*)(Vtb + swzV(d * 128 + ksv * 32 + hi * 16));
            }

        float pA[16];
#pragma unroll
        for (int r = 0; r < 16; ++r) pA[r] = __builtin_amdgcn_exp2f(sc0[r]);
        float tA[8];
#pragma unroll
        for (int i = 0; i < 8; ++i) tA[i] = pA[i] + pA[i + 8];
#pragma unroll
        for (int st = 4; st >= 1; st >>= 1)
#pragma unroll
            for (int i = 0; i < st; ++i) tA[i] = tA[i] + tA[i + st];
        float sumA = tA[0];

        // pa fragments DIRECT from registers (key permutation baked into Vt columns):
        // pa0 elem j = pA[j]  <-> V col  0 + hi*8+j ; pa1 elem j = pA[8+j] <-> V col 16 + hi*8+j
        unsigned int t0w[4], t1w[4];
#pragma unroll
        for (int t = 0; t < 4; ++t) {
            t0w[t] = (unsigned)bfb(pA[2 * t])     | ((unsigned)bfb(pA[2 * t + 1]) << 16);
            t1w[t] = (unsigned)bfb(pA[8 + 2 * t]) | ((unsigned)bfb(pA[8 + 2 * t + 1]) << 16);
        }
        bf16x8 pa0 = *(bf16x8*)t0w;
        bf16x8 pa1 = *(bf16x8*)t1w;

        __builtin_amdgcn_s_setprio(1);
#pragma unroll
        for (int db = 0; db < 4; ++db)
            o[db] = __builtin_amdgcn_mfma_f32_32x32x16_bf16(pa0, vbrA[0 * 4 + db], o[db], 0, 0, 0);
#pragma unroll
        for (int db = 0; db < 4; ++db)
            o[db] = __builtin_amdgcn_mfma_f32_32x32x16_bf16(pa1, vbrA[1 * 4 + db], o[db], 0, 0, 0);
        __builtin_amdgcn_s_setprio(0);

        // ================= phase B: keys 32-63 (V slices 2,3) =================
        bf16x8 vbrB[8];
#pragma unroll
        for (int ksv = 0; ksv < 2; ++ksv)
#pragma unroll
            for (int db = 0; db < 4; ++db) {
                int d = db * 32 + l31;
                vbrB[ksv * 4 + db] = *(const bf16x8*)(Vtb + swzV(d * 128 + (2 + ksv) * 32 + hi * 16));
            }

        float pB[16];
#pragma unroll
        for (int r = 0; r < 16; ++r) pB[r] = __builtin_amdgcn_exp2f(sc1[r]);
        float tB[8];
#pragma unroll
        for (int i = 0; i < 8; ++i) tB[i] = pB[i] + pB[i + 8];
#pragma unroll
        for (int st = 4; st >= 1; st >>= 1)
#pragma unroll
            for (int i = 0; i < st; ++i) tB[i] = tB[i] + tB[i + st];
        l_r += sumA + tB[0];

        unsigned int t2w[4], t3w[4];
#pragma unroll
        for (int t = 0; t < 4; ++t) {
            t2w[t] = (unsigned)bfb(pB[2 * t])     | ((unsigned)bfb(pB[2 * t + 1]) << 16);
            t3w[t] = (unsigned)bfb(pB[8 + 2 * t]) | ((unsigned)bfb(pB[8 + 2 * t + 1]) << 16);
        }
        bf16x8 pa2 = *(bf16x8*)t2w;
        bf16x8 pa3 = *(bf16x8*)t3w;

        __builtin_amdgcn_s_setprio(1);
#pragma unroll
        for (int db = 0; db < 4; ++db)
            o[db] = __builtin_amdgcn_mfma_f32_32x32x16_bf16(pa2, vbrB[0 * 4 + db], o[db], 0, 0, 0);
#pragma unroll
        for (int db = 0; db < 4; ++db)
            o[db] = __builtin_amdgcn_mfma_f32_32x32x16_bf16(pa3, vbrB[1 * 4 + db], o[db], 0, 0, 0);
        __builtin_amdgcn_s_setprio(0);

        __syncthreads();
        cur ^= 1;
    }

    // ---- epilogue: cross-half l reduce, per-row inv broadcast, store ----
    l_r += __shfl_xor(l_r, 32);
    float inv = 1.0f / l_r;
    float invr[16];
#pragma unroll
    for (int r = 0; r < 16; ++r) invr[r] = __shfl(inv, (r & 3) + 8 * (r >> 2) + 4 * hi);
    float* Ob = Out + ((long long)bh * SEQ + qt * 128 + w * 32) * DDIM;
#pragma unroll
    for (int db = 0; db < 4; ++db)
#pragma unroll
        for (int r = 0; r < 16; ++r) {
            int row = (r & 3) + 8 * (r >> 2) + 4 * hi;
            Ob[row * DDIM + db * 32 + l31] = o[db][r] * invr[r];
        }
}

// ---------------- fallback (used only if ws_size too small) ----------------

__device__ __forceinline__ int swz9(int b) { return b ^ (((b >> 9) & 7) << 4); }
__device__ __forceinline__ int swz8f(int b) { return b ^ (((b >> 8) & 7) << 4); }

__global__ __launch_bounds__(256, 4)
void attn_fwd_v1(const float* __restrict__ Q, const float* __restrict__ K,
                 const float* __restrict__ V, float* __restrict__ Out) {
    __shared__ __align__(16) unsigned char lds[16384 + 16384 + 4 * 2048];
    unsigned char* KsB = lds;
    unsigned char* VtB = lds + 16384;
    const int tid = threadIdx.x;
    const int lane = tid & 63;
    const int w = tid >> 6;
    const int l15 = lane & 15;
    const int g = lane >> 4;
    const int qt = blockIdx.x;
    const int bh = blockIdx.y;
    const long long base = (long long)bh * SEQ * DDIM;
    const float* Qb = Q + base + (long long)(qt * 64 + w * 16) * DDIM;
    const float* Kb = K + base;
    const float* Vb = V + base;
    unsigned char* PB = lds + 32768 + w * 2048;
    bf16x8 qf[4];
#pragma unroll
    for (int ks = 0; ks < 4; ++ks) {
        const float* qp = Qb + l15 * DDIM + ks * 32 + g * 8;
        qf[ks] = cvt8s(*(const float4*)qp, *(const float4*)(qp + 4), QSCALE);
    }
    f32x4 o[8];
#pragma unroll
    for (int cb = 0; cb < 8; ++cb) { o[cb][0]=0.f; o[cb][1]=0.f; o[cb][2]=0.f; o[cb][3]=0.f; }
    float m_r[4] = { -INFINITY, -INFINITY, -INFINITY, -INFINITY };
    float l_r[4] = { 0.f, 0.f, 0.f, 0.f };
    for (int kt = 0; kt < SEQ / 64; ++kt) {
        __syncthreads();
#pragma unroll
        for (int it = 0; it < 4; ++it) {
            int chunk = tid + it * 256;
            int key = chunk >> 4;
            int dc = (chunk & 15) * 8;
            const float* kp = Kb + (long long)(kt * 64 + key) * DDIM + dc;
            *(bf16x8*)(KsB + swz9(key * 256 + dc * 2)) = cvt8s(*(const float4*)kp, *(const float4*)(kp + 4), 1.0f);
        }
#pragma unroll
        for (int it = 0; it < 8; ++it) {
            int task = w + it * 4;
            int kq = task >> 1;
            int dh = task & 1;
            int key = kq * 4 + g;
            int d0 = dh * 64 + l15 * 4;
            const float* vp = Vb + (long long)(kt * 64 + key) * DDIM + d0;
            float4 a = *(const float4*)vp;
            *(__bf16*)(VtB + swz8f((d0 + 0) * 128 + key * 2)) = (__bf16)a.x;
            *(__bf16*)(VtB + swz8f((d0 + 1) * 128 + key * 2)) = (__bf16)a.y;
            *(__bf16*)(VtB + swz8f((d0 + 2) * 128 + key * 2)) = (__bf16)a.z;
            *(__bf16*)(VtB + swz8f((d0 + 3) * 128 + key * 2)) = (__bf16)a.w;
        }
        __syncthreads();
        f32x4 sc[4];
#pragma unroll
        for (int c = 0; c < 4; ++c) {
            f32x4 acc; acc[0]=0.f; acc[1]=0.f; acc[2]=0.f; acc[3]=0.f;
#pragma unroll
            for (int ks = 0; ks < 4; ++ks) {
                bf16x8 bf = *(const bf16x8*)(KsB + swz9((c * 16 + l15) * 256 + (ks * 32 + g * 8) * 2));
                acc = __builtin_amdgcn_mfma_f32_16x16x32_bf16(qf[ks], bf, acc, 0, 0, 0);
            }
            sc[c] = acc;
        }
#pragma unroll
        for (int r = 0; r < 4; ++r) {
            float s0 = sc[0][r], s1 = sc[1][r], s2 = sc[2][r], s3 = sc[3][r];
            float mx = fmaxf(fmaxf(s0, s1), fmaxf(s2, s3));
            mx = fmaxf(mx, __shfl_xor(mx, 1));
            mx = fmaxf(mx, __shfl_xor(mx, 2));
            mx = fmaxf(mx, __shfl_xor(mx, 4));
            mx = fmaxf(mx, __shfl_xor(mx, 8));
            float mold = m_r[r];
            float mnew = fmaxf(mold, mx);
            float alpha = __builtin_amdgcn_exp2f(mold - mnew);
            float p0 = __builtin_amdgcn_exp2f(s0 - mnew);
            float p1 = __builtin_amdgcn_exp2f(s1 - mnew);
            float p2 = __builtin_amdgcn_exp2f(s2 - mnew);
            float p3 = __builtin_amdgcn_exp2f(s3 - mnew);
            float sum = (p0 + p1) + (p2 + p3);
            sum += __shfl_xor(sum, 1);
            sum += __shfl_xor(sum, 2);
            sum += __shfl_xor(sum, 4);
            sum += __shfl_xor(sum, 8);
            l_r[r] = l_r[r] * alpha + sum;
            m_r[r] = mnew;
#pragma unroll
            for (int cb = 0; cb < 8; ++cb) o[cb][r] *= alpha;
            int row = g * 4 + r;
            *(__bf16*)(PB + swz8f(row * 128 + (0 * 16 + l15) * 2)) = (__bf16)p0;
            *(__bf16*)(PB + swz8f(row * 128 + (1 * 16 + l15) * 2)) = (__bf16)p1;
            *(__bf16*)(PB + swz8f(row * 128 + (2 * 16 + l15) * 2)) = (__bf16)p2;
            *(__bf16*)(PB + swz8f(row * 128 + (3 * 16 + l15) * 2)) = (__bf16)p3;
        }
#pragma unroll
        for (int kk = 0; kk < 2; ++kk) {
            bf16x8 pa = *(const bf16x8*)(PB + swz8f(l15 * 128 + (kk * 32 + g * 8) * 2));
#pragma unroll
            for (int cb = 0; cb < 8; ++cb) {
                bf16x8 vb = *(const bf16x8*)(VtB + swz8f((cb * 16 + l15) * 128 + (kk * 32 + g * 8) * 2));
                o[cb] = __builtin_amdgcn_mfma_f32_16x16x32_bf16(pa, vb, o[cb], 0, 0, 0);
            }
        }
    }
    float* Ob = Out + base + (long long)(qt * 64 + w * 16) * DDIM;
#pragma unroll
    for (int r = 0; r < 4; ++r) {
        float inv = 1.0f / l_r[r];
        int row = g * 4 + r;
#pragma unroll
        for (int cb = 0; cb < 8; ++cb) Ob[row * DDIM + cb * 16 + l15] = o[cb][r] * inv;
    }
}

extern "C" void kernel_launch(void* const* d_in, const int* in_sizes, int n_in,
                              void* d_out, int out_size, void* d_ws, size_t ws_size,
                              hipStream_t stream) {
    const float* Q = (const float*)d_in[0];
    const float* K = (const float*)d_in[1];
    const float* V = (const float*)d_in[2];
    float* Out = (float*)d_out;

    if (ws_size >= (size_t)32 * 1024 * 1024) {
        unsigned char* ws = (unsigned char*)d_ws;
        unsigned char* kws = ws;
        unsigned char* vtws = ws + (size_t)16 * 1024 * 1024;
        prep_kv<<<1024, 256, 0, stream>>>(K, V, kws, vtws);
        attn_v11<<<512, 256, 0, stream>>>(Q, kws, vtws, Out);
    } else {
        attn_fwd_v1<<<dim3(32, 32), 256, 0, stream>>>(Q, K, V, Out);
    }
}

// Round 15
// 91.801 us; speedup vs baseline: 1.0683x; 1.0323x over previous
//
#include <hip/hip_runtime.h>
#include <hip/hip_bf16.h>
#include <math.h>

#define SEQ   2048
#define DDIM  128
#define NBH   32
#define KVB   64
#define NT    (SEQ / KVB)        // 32 kv tiles
#define QSCALE (0.08838834764831845f * 1.4426950408889634f)  // 1/sqrt(128) * log2(e)

typedef __bf16 bf16x8 __attribute__((ext_vector_type(8)));
typedef float  f32x4  __attribute__((ext_vector_type(4)));
typedef float  f32x16 __attribute__((ext_vector_type(16)));
typedef unsigned short u16x8 __attribute__((ext_vector_type(8)));

// Ks tile: byte = key*256 + off. Read swizzle: 16B-slot ^= key&15 (baked in prep).
__device__ __forceinline__ int swzK(int b) { return b ^ (((b >> 8) & 15) << 4); }

__device__ __forceinline__ void gload16(const void* g, void* l) {
    __builtin_amdgcn_global_load_lds(
        (const __attribute__((address_space(1))) unsigned int*)g,
        (__attribute__((address_space(3))) unsigned int*)l, 16, 0, 0);
}
__device__ __forceinline__ unsigned short bfb(float x) {
    return __builtin_bit_cast(unsigned short, (__bf16)x);
}
__device__ __forceinline__ bf16x8 cvt8s(float4 a, float4 b, float s) {
    bf16x8 v;
    v[0] = (__bf16)(a.x * s); v[1] = (__bf16)(a.y * s);
    v[2] = (__bf16)(a.z * s); v[3] = (__bf16)(a.w * s);
    v[4] = (__bf16)(b.x * s); v[5] = (__bf16)(b.y * s);
    v[6] = (__bf16)(b.z * s); v[7] = (__bf16)(b.w * s);
    return v;
}

// ---------------- fused prepass ----------------
// K: fp32 -> bf16 with slot^=key&15 baked (unchanged).
// V: key-PERMUTED bf16, NEW slot-major layout [bh][kt][slot][d] (slot<8, d<128, 16B chunks):
//    16B chunk (slot,d) holds columns v = slot*8+j at dim d, where column v holds key
//    perm_inv(v) = (v&32) + 16*((v>>4)&1) + 8*((v>>2)&1) + 4*((v>>3)&1) + (v&3)
//    (perm_inv HW-verified in round 13). Slot-major kills the 4-way V-read bank conflict:
//    LDS row stride 128B == one bank cycle, so the old d-major layout aliased 4 lanes/bank.
__global__ __launch_bounds__(256)
void prep_kv(const float* __restrict__ K, const float* __restrict__ V,
             unsigned char* __restrict__ kws, unsigned char* __restrict__ vtws) {
    const int blk = blockIdx.x, tid = threadIdx.x;

#pragma unroll
    for (int it = 0; it < 4; ++it) {
        int chunk = blk * 1024 + it * 256 + tid;   // 0 .. 1048575 (16B chunks)
        int c   = chunk & 15;
        int row = chunk >> 4;                      // bh*2048 + key
        int key = row & (SEQ - 1);
        const float* s = K + (long long)row * DDIM + c * 8;
        float4 a = *(const float4*)s;
        float4 b = *(const float4*)(s + 4);
        int c2 = c ^ (key & 15);                   // == swzK on tile byte key_local*256 + c*16
        *(bf16x8*)(kws + (long long)row * 256 + c2 * 16) = cvt8s(a, b, 1.0f);
    }

    __shared__ float vt[64][129];
    const int kt64 = blk & 31, bh = blk >> 5;
#pragma unroll
    for (int it = 0; it < 4; ++it) {
        int chunk = tid + it * 256;                // 0..1023
        int key = chunk >> 4, c = chunk & 15;
        const float* s = V + ((long long)(bh * SEQ + kt64 * 64 + key)) * DDIM + c * 8;
        float4 a = *(const float4*)s;
        float4 b = *(const float4*)(s + 4);
        vt[key][c * 8 + 0] = a.x; vt[key][c * 8 + 1] = a.y;
        vt[key][c * 8 + 2] = a.z; vt[key][c * 8 + 3] = a.w;
        vt[key][c * 8 + 4] = b.x; vt[key][c * 8 + 5] = b.y;
        vt[key][c * 8 + 6] = b.z; vt[key][c * 8 + 7] = b.w;
    }
    __syncthreads();
    // kt64 covers 2 kv-tiles (kt = kt64*2 + half32): keys half32*32 + 0..31 per tile.
    // Chunk (slot,d) of tile kt holds v-cols slot*8+j -> key perm_inv within that tile.
#pragma unroll
    for (int it = 0; it < 8; ++it) {
        int pair = it * 256 + tid;                 // 0..2047: tile-half * 1024 + slot*128 + d
        int d = pair & 127;
        int sl = (pair >> 7) & 7;
        int half32 = pair >> 10;                   // which 32-key tile of this 64-key group
        u16x8 u;
#pragma unroll
        for (int j = 0; j < 8; ++j) {
            int v = sl * 8 + j;                    // v < 64 here uses only v<32 bits + half32
            int vv = v & 31;
            int key = half32 * 32 + (((vv >> 4) & 1) << 4) + (((vv >> 2) & 1) << 3)
                    + (((vv >> 3) & 1) << 2) + (vv & 3);
            u[j] = bfb(vt[key][d]);
        }
        // ws byte: bh*524288 + kt*8192? NO — keep 16KB per 64-key kt to match stage:
        // layout per KVB=64 tile: [slot<8][d<128] with slot covering v 0..63 -> 8 slots of 8 v.
        // v = sl*8+j only reaches 0..63 when combined: actual v = half32*32 + sl*8+j requires sl<4.
        // Simpler: treat tile kt (64 keys): slot s64 = v>>3 (0..7), v = s64*8+j.
        (void)u; // placeholder, real store below
    }
    // --- real store loop (tile-major, v = sl*8+j over 64 keys) ---
#pragma unroll
    for (int it = 0; it < 8; ++it) {
        int pair = it * 256 + tid;                 // 0..2047 = half32*1024 + sl*128 + d
        int d = pair & 127;
        int sl = (pair >> 7) & 7;                  // slot within the 64-key tile (v = sl*8+j)
        int half32 = pair >> 10;                   // NOT a tile split — see below
        // For KVB=64 tiles, kt64 IS the tile: v in 0..63, slot = v>>3 in 0..7.
        // We only need one pass over (sl 0..7, d 0..127) = 1024 chunks; the it<8 loop
        // double-covers, so skip the second half.
        if (half32) continue;
        u16x8 u;
#pragma unroll
        for (int j = 0; j < 8; ++j) {
            int v = sl * 8 + j;                    // 0..63
            int key = (v & 32) + (((v >> 4) & 1) << 4) + (((v >> 2) & 1) << 3)
                    + (((v >> 3) & 1) << 2) + (v & 3);
            u[j] = bfb(vt[key][d]);
        }
        *(u16x8*)(vtws + (long long)bh * 524288 + (long long)kt64 * 16384 + sl * 2048 + d * 16) = u;
    }
}

// ---- main: v11 + slot-major Vt (conflict-free V reads, linear V staging) ----

__global__ __launch_bounds__(256, 2)
void attn_v15(const float* __restrict__ Q, const unsigned char* __restrict__ kws,
              const unsigned char* __restrict__ vtws, float* __restrict__ Out) {
    __shared__ __align__(16) unsigned char lds[2][32768];   // per buf: Ks 16K | Vt 16K

    const int tid = threadIdx.x;
    const int lane = tid & 63;
    const int w = tid >> 6;                                 // 0..3
    const int l31 = lane & 31, hi = lane >> 5;

    // bijective XCD swizzle: 512 blocks -> 64-block chunks per XCD (4 bh each)
    const int bid = blockIdx.x;
    const int swz = ((bid & 7) << 6) | (bid >> 3);
    const int qt = swz & 15;
    const int bh = swz >> 4;

    const unsigned char* kbh = kws + (long long)bh * 524288;
    const unsigned char* vbh = vtws + (long long)bh * 524288;

    // ---- Q frags (B operand of QK): q = qt*128 + w*32 + l31; k-slice d = ks*16 + hi*8 + j ----
    bf16x8 qf[8];
    const float* Qb = Q + ((long long)bh * SEQ + qt * 128 + w * 32 + l31) * DDIM;
#pragma unroll
    for (int ks = 0; ks < 8; ++ks) {
        const float* qp = Qb + ks * 16 + hi * 8;
        qf[ks] = cvt8s(*(const float4*)qp, *(const float4*)(qp + 4), QSCALE);
    }

    f32x16 o[4];
#pragma unroll
    for (int db = 0; db < 4; ++db)
#pragma unroll
        for (int r = 0; r < 16; ++r) o[db][r] = 0.f;
    float l_r = 0.f;   // per-lane partial sum of exp2(score); cross-half reduce at end

    auto stage = [&](int buf, int kt) {
        unsigned char* Ksb = &lds[buf][0];
        unsigned char* Vtb = &lds[buf][16384];
#pragma unroll
        for (int i = 0; i < 4; ++i) {
            int sg = i * 256 + tid;                          // 0..1023
            gload16(kbh + kt * 16384 + sg * 16, Ksb + sg * 16);  // linear (swz baked in prep)
        }
#pragma unroll
        for (int i = 0; i < 4; ++i) {
            int sg = i * 256 + tid;                          // linear: slot-major layout
            gload16(vbh + kt * 16384 + sg * 16, Vtb + sg * 16);
        }
    };

    stage(0, 0);
    __syncthreads();
    int cur = 0;

#pragma unroll 1
    for (int kt = 0; kt < NT; ++kt) {
        if (kt + 1 < NT) stage(cur ^ 1, kt + 1);

        unsigned char* Ksb = &lds[cur][0];
        unsigned char* Vtb = &lds[cur][16384];

        // ---- QK^T both key-halves (32x32x16): lane q=l31; C-row=(reg&3)+8(reg>>2)+4hi ----
        f32x16 sc0, sc1;
#pragma unroll
        for (int r = 0; r < 16; ++r) { sc0[r] = 0.f; sc1[r] = 0.f; }
        __builtin_amdgcn_s_setprio(1);
#pragma unroll
        for (int ks = 0; ks < 8; ++ks) {
            bf16x8 kf0 = *(const bf16x8*)(Ksb + swzK((0 * 32 + l31) * 256 + ks * 32 + hi * 16));
            bf16x8 kf1 = *(const bf16x8*)(Ksb + swzK((1 * 32 + l31) * 256 + ks * 32 + hi * 16));
            sc0 = __builtin_amdgcn_mfma_f32_32x32x16_bf16(kf0, qf[ks], sc0, 0, 0, 0);
            sc1 = __builtin_amdgcn_mfma_f32_32x32x16_bf16(kf1, qf[ks], sc1, 0, 0, 0);
        }
        __builtin_amdgcn_s_setprio(0);

        // ================= phase A: keys 0-31 (v-cols 0-31 = slots 0-3) =================
        bf16x8 vbrA[8];
#pragma unroll
        for (int ksv = 0; ksv < 2; ++ksv)
#pragma unroll
            for (int db = 0; db < 4; ++db)
                vbrA[ksv * 4 + db] = *(const bf16x8*)(Vtb + (ksv * 2 + hi) * 2048 + (db * 32 + l31) * 16);

        float pA[16];
#pragma unroll
        for (int r = 0; r < 16; ++r) pA[r] = __builtin_amdgcn_exp2f(sc0[r]);
        float tA[8];
#pragma unroll
        for (int i = 0; i < 8; ++i) tA[i] = pA[i] + pA[i + 8];
#pragma unroll
        for (int st = 4; st >= 1; st >>= 1)
#pragma unroll
            for (int i = 0; i < st; ++i) tA[i] = tA[i] + tA[i + st];
        float sumA = tA[0];

        unsigned int t0w[4], t1w[4];
#pragma unroll
        for (int t = 0; t < 4; ++t) {
            t0w[t] = (unsigned)bfb(pA[2 * t])     | ((unsigned)bfb(pA[2 * t + 1]) << 16);
            t1w[t] = (unsigned)bfb(pA[8 + 2 * t]) | ((unsigned)bfb(pA[8 + 2 * t + 1]) << 16);
        }
        bf16x8 pa0 = *(bf16x8*)t0w;
        bf16x8 pa1 = *(bf16x8*)t1w;

        __builtin_amdgcn_s_setprio(1);
#pragma unroll
        for (int db = 0; db < 4; ++db)
            o[db] = __builtin_amdgcn_mfma_f32_32x32x16_bf16(pa0, vbrA[0 * 4 + db], o[db], 0, 0, 0);
#pragma unroll
        for (int db = 0; db < 4; ++db)
            o[db] = __builtin_amdgcn_mfma_f32_32x32x16_bf16(pa1, vbrA[1 * 4 + db], o[db], 0, 0, 0);
        __builtin_amdgcn_s_setprio(0);

        // ================= phase B: keys 32-63 (v-cols 32-63 = slots 4-7) =================
        bf16x8 vbrB[8];
#pragma unroll
        for (int ksv = 0; ksv < 2; ++ksv)
#pragma unroll
            for (int db = 0; db < 4; ++db)
                vbrB[ksv * 4 + db] = *(const bf16x8*)(Vtb + ((2 + ksv) * 2 + hi) * 2048 + (db * 32 + l31) * 16);

        float pB[16];
#pragma unroll
        for (int r = 0; r < 16; ++r) pB[r] = __builtin_amdgcn_exp2f(sc1[r]);
        float tB[8];
#pragma unroll
        for (int i = 0; i < 8; ++i) tB[i] = pB[i] + pB[i + 8];
#pragma unroll
        for (int st = 4; st >= 1; st >>= 1)
#pragma unroll
            for (int i = 0; i < st; ++i) tB[i] = tB[i] + tB[i + st];
        l_r += sumA + tB[0];

        unsigned int t2w[4], t3w[4];
#pragma unroll
        for (int t = 0; t < 4; ++t) {
            t2w[t] = (unsigned)bfb(pB[2 * t])     | ((unsigned)bfb(pB[2 * t + 1]) << 16);
            t3w[t] = (unsigned)bfb(pB[8 + 2 * t]) | ((unsigned)bfb(pB[8 + 2 * t + 1]) << 16);
        }
        bf16x8 pa2 = *(bf16x8*)t2w;
        bf16x8 pa3 = *(bf16x8*)t3w;

        __builtin_amdgcn_s_setprio(1);
#pragma unroll
        for (int db = 0; db < 4; ++db)
            o[db] = __builtin_amdgcn_mfma_f32_32x32x16_bf16(pa2, vbrB[0 * 4 + db], o[db], 0, 0, 0);
#pragma unroll
        for (int db = 0; db < 4; ++db)
            o[db] = __builtin_amdgcn_mfma_f32_32x32x16_bf16(pa3, vbrB[1 * 4 + db], o[db], 0, 0, 0);
        __builtin_amdgcn_s_setprio(0);

        __syncthreads();
        cur ^= 1;
    }

    // ---- epilogue: cross-half l reduce, per-row inv broadcast, store ----
    l_r += __shfl_xor(l_r, 32);
    float inv = 1.0f / l_r;
    float invr[16];
#pragma unroll
    for (int r = 0; r < 16; ++r) invr[r] = __shfl(inv, (r & 3) + 8 * (r >> 2) + 4 * hi);
    float* Ob = Out + ((long long)bh * SEQ + qt * 128 + w * 32) * DDIM;
#pragma unroll
    for (int db = 0; db < 4; ++db)
#pragma unroll
        for (int r = 0; r < 16; ++r) {
            int row = (r & 3) + 8 * (r >> 2) + 4 * hi;
            Ob[row * DDIM + db * 32 + l31] = o[db][r] * invr[r];
        }
}

// ---------------- fallback (used only if ws_size too small) ----------------

__device__ __forceinline__ int swz9(int b) { return b ^ (((b >> 9) & 7) << 4); }
__device__ __forceinline__ int swz8f(int b) { return b ^ (((b >> 8) & 7) << 4); }

__global__ __launch_bounds__(256, 4)
void attn_fwd_v1(const float* __restrict__ Q, const float* __restrict__ K,
                 const float* __restrict__ V, float* __restrict__ Out) {
    __shared__ __align__(16) unsigned char lds[16384 + 16384 + 4 * 2048];
    unsigned char* KsB = lds;
    unsigned char* VtB = lds + 16384;
    const int tid = threadIdx.x;
    const int lane = tid & 63;
    const int w = tid >> 6;
    const int l15 = lane & 15;
    const int g = lane >> 4;
    const int qt = blockIdx.x;
    const int bh = blockIdx.y;
    const long long base = (long long)bh * SEQ * DDIM;
    const float* Qb = Q + base + (long long)(qt * 64 + w * 16) * DDIM;
    const float* Kb = K + base;
    const float* Vb = V + base;
    unsigned char* PB = lds + 32768 + w * 2048;
    bf16x8 qf[4];
#pragma unroll
    for (int ks = 0; ks < 4; ++ks) {
        const float* qp = Qb + l15 * DDIM + ks * 32 + g * 8;
        qf[ks] = cvt8s(*(const float4*)qp, *(const float4*)(qp + 4), QSCALE);
    }
    f32x4 o[8];
#pragma unroll
    for (int cb = 0; cb < 8; ++cb) { o[cb][0]=0.f; o[cb][1]=0.f; o[cb][2]=0.f; o[cb][3]=0.f; }
    float m_r[4] = { -INFINITY, -INFINITY, -INFINITY, -INFINITY };
    float l_r[4] = { 0.f, 0.f, 0.f, 0.f };
    for (int kt = 0; kt < SEQ / 64; ++kt) {
        __syncthreads();
#pragma unroll
        for (int it = 0; it < 4; ++it) {
            int chunk = tid + it * 256;
            int key = chunk >> 4;
            int dc = (chunk & 15) * 8;
            const float* kp = Kb + (long long)(kt * 64 + key) * DDIM + dc;
            *(bf16x8*)(KsB + swz9(key * 256 + dc * 2)) = cvt8s(*(const float4*)kp, *(const float4*)(kp + 4), 1.0f);
        }
#pragma unroll
        for (int it = 0; it < 8; ++it) {
            int task = w + it * 4;
            int kq = task >> 1;
            int dh = task & 1;
            int key = kq * 4 + g;
            int d0 = dh * 64 + l15 * 4;
            const float* vp = Vb + (long long)(kt * 64 + key) * DDIM + d0;
            float4 a = *(const float4*)vp;
            *(__bf16*)(VtB + swz8f((d0 + 0) * 128 + key * 2)) = (__bf16)a.x;
            *(__bf16*)(VtB + swz8f((d0 + 1) * 128 + key * 2)) = (__bf16)a.y;
            *(__bf16*)(VtB + swz8f((d0 + 2) * 128 + key * 2)) = (__bf16)a.z;
            *(__bf16*)(VtB + swz8f((d0 + 3) * 128 + key * 2)) = (__bf16)a.w;
        }
        __syncthreads();
        f32x4 sc[4];
#pragma unroll
        for (int c = 0; c < 4; ++c) {
            f32x4 acc; acc[0]=0.f; acc[1]=0.f; acc[2]=0.f; acc[3]=0.f;
#pragma unroll
            for (int ks = 0; ks < 4; ++ks) {
                bf16x8 bf = *(const bf16x8*)(KsB + swz9((c * 16 + l15) * 256 + (ks * 32 + g * 8) * 2));
                acc = __builtin_amdgcn_mfma_f32_16x16x32_bf16(qf[ks], bf, acc, 0, 0, 0);
            }
            sc[c] = acc;
        }
#pragma unroll
        for (int r = 0; r < 4; ++r) {
            float s0 = sc[0][r], s1 = sc[1][r], s2 = sc[2][r], s3 = sc[3][r];
            float mx = fmaxf(fmaxf(s0, s1), fmaxf(s2, s3));
            mx = fmaxf(mx, __shfl_xor(mx, 1));
            mx = fmaxf(mx, __shfl_xor(mx, 2));
            mx = fmaxf(mx, __shfl_xor(mx, 4));
            mx = fmaxf(mx, __shfl_xor(mx, 8));
            float mold = m_r[r];
            float mnew = fmaxf(mold, mx);
            float alpha = __builtin_amdgcn_exp2f(mold - mnew);
            float p0 = __builtin_amdgcn_exp2f(s0 - mnew);
            float p1 = __builtin_amdgcn_exp2f(s1 - mnew);
            float p2 = __builtin_amdgcn_exp2f(s2 - mnew);
            float p3 = __builtin_amdgcn_exp2f(s3 - mnew);
            float sum = (p0 + p1) + (p2 + p3);
            sum += __shfl_xor(sum, 1);
            sum += __shfl_xor(sum, 2);
            sum += __shfl_xor(sum, 4);
            sum += __shfl_xor(sum, 8);
            l_r[r] = l_r[r] * alpha + sum;
            m_r[r] = mnew;
#pragma unroll
            for (int cb = 0; cb < 8; ++cb) o[cb][r] *= alpha;
            int row = g * 4 + r;
            *(__bf16*)(PB + swz8f(row * 128 + (0 * 16 + l15) * 2)) = (__bf16)p0;
            *(__bf16*)(PB + swz8f(row * 128 + (1 * 16 + l15) * 2)) = (__bf16)p1;
            *(__bf16*)(PB + swz8f(row * 128 + (2 * 16 + l15) * 2)) = (__bf16)p2;
            *(__bf16*)(PB + swz8f(row * 128 + (3 * 16 + l15) * 2)) = (__bf16)p3;
        }
#pragma unroll
        for (int kk = 0; kk < 2; ++kk) {
            bf16x8 pa = *(const bf16x8*)(PB + swz8f(l15 * 128 + (kk * 32 + g * 8) * 2));
#pragma unroll
            for (int cb = 0; cb < 8; ++cb) {
                bf16x8 vb = *(const bf16x8*)(VtB + swz8f((cb * 16 + l15) * 128 + (kk * 32 + g * 8) * 2));
                o[cb] = __builtin_amdgcn_mfma_f32_16x16x32_bf16(pa, vb, o[cb], 0, 0, 0);
            }
        }
    }
    float* Ob = Out + base + (long long)(qt * 64 + w * 16) * DDIM;
#pragma unroll
    for (int r = 0; r < 4; ++r) {
        float inv = 1.0f / l_r[r];
        int row = g * 4 + r;
#pragma unroll
        for (int cb = 0; cb < 8; ++cb) Ob[row * DDIM + cb * 16 + l15] = o[cb][r] * inv;
    }
}

extern "C" void kernel_launch(void* const* d_in, const int* in_sizes, int n_in,
                              void* d_out, int out_size, void* d_ws, size_t ws_size,
                              hipStream_t stream) {
    const float* Q = (const float*)d_in[0];
    const float* K = (const float*)d_in[1];
    const float* V = (const float*)d_in[2];
    float* Out = (float*)d_out;

    if (ws_size >= (size_t)32 * 1024 * 1024) {
        unsigned char* ws = (unsigned char*)d_ws;
        unsigned char* kws = ws;
        unsigned char* vtws = ws + (size_t)16 * 1024 * 1024;
        prep_kv<<<1024, 256, 0, stream>>>(K, V, kws, vtws);
        attn_v15<<<512, 256, 0, stream>>>(Q, kws, vtws, Out);
    } else {
        attn_fwd_v1<<<dim3(32, 32), 256, 0, stream>>>(Q, K, V, Out);
    }
}

// Round 16
// 90.249 us; speedup vs baseline: 1.0867x; 1.0172x over previous
//
#include <hip/hip_runtime.h>
#include <hip/hip_bf16.h>
#include <math.h>

#define SEQ   2048
#define DDIM  128
#define NBH   32
#define KVB   64
#define NT    (SEQ / KVB)        // 32 kv tiles
#define QSCALE (0.08838834764831845f * 1.4426950408889634f)  // 1/sqrt(128) * log2(e)

typedef __bf16 bf16x8 __attribute__((ext_vector_type(8)));
typedef float  f32x4  __attribute__((ext_vector_type(4)));
typedef float  f32x16 __attribute__((ext_vector_type(16)));
typedef unsigned short u16x8 __attribute__((ext_vector_type(8)));

// Ks tile: byte = key*256 + off. Read swizzle: 16B-slot ^= key&15 (baked in prep).
__device__ __forceinline__ int swzK(int b) { return b ^ (((b >> 8) & 15) << 4); }

__device__ __forceinline__ void gload16(const void* g, void* l) {
    __builtin_amdgcn_global_load_lds(
        (const __attribute__((address_space(1))) unsigned int*)g,
        (__attribute__((address_space(3))) unsigned int*)l, 16, 0, 0);
}
__device__ __forceinline__ unsigned short bfb(float x) {
    return __builtin_bit_cast(unsigned short, (__bf16)x);
}
__device__ __forceinline__ bf16x8 cvt8s(float4 a, float4 b, float s) {
    bf16x8 v;
    v[0] = (__bf16)(a.x * s); v[1] = (__bf16)(a.y * s);
    v[2] = (__bf16)(a.z * s); v[3] = (__bf16)(a.w * s);
    v[4] = (__bf16)(b.x * s); v[5] = (__bf16)(b.y * s);
    v[6] = (__bf16)(b.z * s); v[7] = (__bf16)(b.w * s);
    return v;
}

// ---------------- fused prepass (identical to round-15 working version) ----------------
// K: fp32 -> bf16 with slot^=key&15 baked.
// V: key-PERMUTED bf16, slot-major layout [bh][kt][slot<8][d<128] (16B chunks):
//    chunk (slot,d) holds v-cols v = slot*8+j at dim d; column v holds key
//    perm_inv(v) = (v&32) + 16*((v>>4)&1) + 8*((v>>2)&1) + 4*((v>>3)&1) + (v&3).
//    Slot-major kills the 4-way V-read bank conflict (row stride 128B == one bank cycle).
__global__ __launch_bounds__(256)
void prep_kv(const float* __restrict__ K, const float* __restrict__ V,
             unsigned char* __restrict__ kws, unsigned char* __restrict__ vtws) {
    const int blk = blockIdx.x, tid = threadIdx.x;

#pragma unroll
    for (int it = 0; it < 4; ++it) {
        int chunk = blk * 1024 + it * 256 + tid;   // 0 .. 1048575 (16B chunks)
        int c   = chunk & 15;
        int row = chunk >> 4;                      // bh*2048 + key
        int key = row & (SEQ - 1);
        const float* s = K + (long long)row * DDIM + c * 8;
        float4 a = *(const float4*)s;
        float4 b = *(const float4*)(s + 4);
        int c2 = c ^ (key & 15);                   // == swzK on tile byte key_local*256 + c*16
        *(bf16x8*)(kws + (long long)row * 256 + c2 * 16) = cvt8s(a, b, 1.0f);
    }

    __shared__ float vt[64][129];
    const int kt64 = blk & 31, bh = blk >> 5;
#pragma unroll
    for (int it = 0; it < 4; ++it) {
        int chunk = tid + it * 256;                // 0..1023
        int key = chunk >> 4, c = chunk & 15;
        const float* s = V + ((long long)(bh * SEQ + kt64 * 64 + key)) * DDIM + c * 8;
        float4 a = *(const float4*)s;
        float4 b = *(const float4*)(s + 4);
        vt[key][c * 8 + 0] = a.x; vt[key][c * 8 + 1] = a.y;
        vt[key][c * 8 + 2] = a.z; vt[key][c * 8 + 3] = a.w;
        vt[key][c * 8 + 4] = b.x; vt[key][c * 8 + 5] = b.y;
        vt[key][c * 8 + 6] = b.z; vt[key][c * 8 + 7] = b.w;
    }
    __syncthreads();
#pragma unroll
    for (int it = 0; it < 4; ++it) {
        int pair = it * 256 + tid;                 // 0..1023 = sl*128 + d
        int d = pair & 127;
        int sl = pair >> 7;                        // slot 0..7 (v = sl*8+j over 64 keys)
        u16x8 u;
#pragma unroll
        for (int j = 0; j < 8; ++j) {
            int v = sl * 8 + j;                    // 0..63
            int key = (v & 32) + (((v >> 4) & 1) << 4) + (((v >> 2) & 1) << 3)
                    + (((v >> 3) & 1) << 2) + (v & 3);
            u[j] = bfb(vt[key][d]);
        }
        *(u16x8*)(vtws + (long long)bh * 524288 + (long long)kt64 * 16384 + sl * 2048 + d * 16) = u;
    }
}

// ---- main: v15 + stage() moved after QK (keeps QK-start free of staging addr-VALU) ----

__global__ __launch_bounds__(256, 2)
void attn_v16(const float* __restrict__ Q, const unsigned char* __restrict__ kws,
              const unsigned char* __restrict__ vtws, float* __restrict__ Out) {
    __shared__ __align__(16) unsigned char lds[2][32768];   // per buf: Ks 16K | Vt 16K

    const int tid = threadIdx.x;
    const int lane = tid & 63;
    const int w = tid >> 6;                                 // 0..3
    const int l31 = lane & 31, hi = lane >> 5;

    // bijective XCD swizzle: 512 blocks -> 64-block chunks per XCD (4 bh each)
    const int bid = blockIdx.x;
    const int swz = ((bid & 7) << 6) | (bid >> 3);
    const int qt = swz & 15;
    const int bh = swz >> 4;

    const unsigned char* kbh = kws + (long long)bh * 524288;
    const unsigned char* vbh = vtws + (long long)bh * 524288;

    // ---- Q frags (B operand of QK): q = qt*128 + w*32 + l31; k-slice d = ks*16 + hi*8 + j ----
    bf16x8 qf[8];
    const float* Qb = Q + ((long long)bh * SEQ + qt * 128 + w * 32 + l31) * DDIM;
#pragma unroll
    for (int ks = 0; ks < 8; ++ks) {
        const float* qp = Qb + ks * 16 + hi * 8;
        qf[ks] = cvt8s(*(const float4*)qp, *(const float4*)(qp + 4), QSCALE);
    }

    f32x16 o[4];
#pragma unroll
    for (int db = 0; db < 4; ++db)
#pragma unroll
        for (int r = 0; r < 16; ++r) o[db][r] = 0.f;
    float l_r = 0.f;   // per-lane partial sum of exp2(score); cross-half reduce at end

    auto stage = [&](int buf, int kt) {
        unsigned char* Ksb = &lds[buf][0];
        unsigned char* Vtb = &lds[buf][16384];
#pragma unroll
        for (int i = 0; i < 4; ++i) {
            int sg = i * 256 + tid;                          // 0..1023
            gload16(kbh + kt * 16384 + sg * 16, Ksb + sg * 16);  // linear (swz baked in prep)
        }
#pragma unroll
        for (int i = 0; i < 4; ++i) {
            int sg = i * 256 + tid;                          // linear: slot-major layout
            gload16(vbh + kt * 16384 + sg * 16, Vtb + sg * 16);
        }
    };

    stage(0, 0);
    __syncthreads();
    int cur = 0;

#pragma unroll 1
    for (int kt = 0; kt < NT; ++kt) {
        unsigned char* Ksb = &lds[cur][0];
        unsigned char* Vtb = &lds[cur][16384];

        // ---- QK^T both key-halves (32x32x16): lane q=l31; C-row=(reg&3)+8(reg>>2)+4hi ----
        f32x16 sc0, sc1;
#pragma unroll
        for (int r = 0; r < 16; ++r) { sc0[r] = 0.f; sc1[r] = 0.f; }
        __builtin_amdgcn_s_setprio(1);
#pragma unroll
        for (int ks = 0; ks < 8; ++ks) {
            bf16x8 kf0 = *(const bf16x8*)(Ksb + swzK((0 * 32 + l31) * 256 + ks * 32 + hi * 16));
            bf16x8 kf1 = *(const bf16x8*)(Ksb + swzK((1 * 32 + l31) * 256 + ks * 32 + hi * 16));
            sc0 = __builtin_amdgcn_mfma_f32_32x32x16_bf16(kf0, qf[ks], sc0, 0, 0, 0);
            sc1 = __builtin_amdgcn_mfma_f32_32x32x16_bf16(kf1, qf[ks], sc1, 0, 0, 0);
        }
        __builtin_amdgcn_s_setprio(0);

        // ---- prefetch next tile AFTER QK: staging addr-VALU off the QK critical path;
        //      loads still have softmax+PV (~2/3 of the iteration) to land before barrier ----
        if (kt + 1 < NT) stage(cur ^ 1, kt + 1);

        // ================= phase A: keys 0-31 (v-cols 0-31 = slots 0-3) =================
        bf16x8 vbrA[8];
#pragma unroll
        for (int ksv = 0; ksv < 2; ++ksv)
#pragma unroll
            for (int db = 0; db < 4; ++db)
                vbrA[ksv * 4 + db] = *(const bf16x8*)(Vtb + (ksv * 2 + hi) * 2048 + (db * 32 + l31) * 16);

        float pA[16];
#pragma unroll
        for (int r = 0; r < 16; ++r) pA[r] = __builtin_amdgcn_exp2f(sc0[r]);
        float tA[8];
#pragma unroll
        for (int i = 0; i < 8; ++i) tA[i] = pA[i] + pA[i + 8];
#pragma unroll
        for (int st = 4; st >= 1; st >>= 1)
#pragma unroll
            for (int i = 0; i < st; ++i) tA[i] = tA[i] + tA[i + st];
        float sumA = tA[0];

        unsigned int t0w[4], t1w[4];
#pragma unroll
        for (int t = 0; t < 4; ++t) {
            t0w[t] = (unsigned)bfb(pA[2 * t])     | ((unsigned)bfb(pA[2 * t + 1]) << 16);
            t1w[t] = (unsigned)bfb(pA[8 + 2 * t]) | ((unsigned)bfb(pA[8 + 2 * t + 1]) << 16);
        }
        bf16x8 pa0 = *(bf16x8*)t0w;
        bf16x8 pa1 = *(bf16x8*)t1w;

        __builtin_amdgcn_s_setprio(1);
#pragma unroll
        for (int db = 0; db < 4; ++db)
            o[db] = __builtin_amdgcn_mfma_f32_32x32x16_bf16(pa0, vbrA[0 * 4 + db], o[db], 0, 0, 0);
#pragma unroll
        for (int db = 0; db < 4; ++db)
            o[db] = __builtin_amdgcn_mfma_f32_32x32x16_bf16(pa1, vbrA[1 * 4 + db], o[db], 0, 0, 0);
        __builtin_amdgcn_s_setprio(0);

        // ================= phase B: keys 32-63 (v-cols 32-63 = slots 4-7) =================
        bf16x8 vbrB[8];
#pragma unroll
        for (int ksv = 0; ksv < 2; ++ksv)
#pragma unroll
            for (int db = 0; db < 4; ++db)
                vbrB[ksv * 4 + db] = *(const bf16x8*)(Vtb + ((2 + ksv) * 2 + hi) * 2048 + (db * 32 + l31) * 16);

        float pB[16];
#pragma unroll
        for (int r = 0; r < 16; ++r) pB[r] = __builtin_amdgcn_exp2f(sc1[r]);
        float tB[8];
#pragma unroll
        for (int i = 0; i < 8; ++i) tB[i] = pB[i] + pB[i + 8];
#pragma unroll
        for (int st = 4; st >= 1; st >>= 1)
#pragma unroll
            for (int i = 0; i < st; ++i) tB[i] = tB[i] + tB[i + st];
        l_r += sumA + tB[0];

        unsigned int t2w[4], t3w[4];
#pragma unroll
        for (int t = 0; t < 4; ++t) {
            t2w[t] = (unsigned)bfb(pB[2 * t])     | ((unsigned)bfb(pB[2 * t + 1]) << 16);
            t3w[t] = (unsigned)bfb(pB[8 + 2 * t]) | ((unsigned)bfb(pB[8 + 2 * t + 1]) << 16);
        }
        bf16x8 pa2 = *(bf16x8*)t2w;
        bf16x8 pa3 = *(bf16x8*)t3w;

        __builtin_amdgcn_s_setprio(1);
#pragma unroll
        for (int db = 0; db < 4; ++db)
            o[db] = __builtin_amdgcn_mfma_f32_32x32x16_bf16(pa2, vbrB[0 * 4 + db], o[db], 0, 0, 0);
#pragma unroll
        for (int db = 0; db < 4; ++db)
            o[db] = __builtin_amdgcn_mfma_f32_32x32x16_bf16(pa3, vbrB[1 * 4 + db], o[db], 0, 0, 0);
        __builtin_amdgcn_s_setprio(0);

        __syncthreads();
        cur ^= 1;
    }

    // ---- epilogue: cross-half l reduce, per-row inv broadcast, store ----
    l_r += __shfl_xor(l_r, 32);
    float inv = 1.0f / l_r;
    float invr[16];
#pragma unroll
    for (int r = 0; r < 16; ++r) invr[r] = __shfl(inv, (r & 3) + 8 * (r >> 2) + 4 * hi);
    float* Ob = Out + ((long long)bh * SEQ + qt * 128 + w * 32) * DDIM;
#pragma unroll
    for (int db = 0; db < 4; ++db)
#pragma unroll
        for (int r = 0; r < 16; ++r) {
            int row = (r & 3) + 8 * (r >> 2) + 4 * hi;
            Ob[row * DDIM + db * 32 + l31] = o[db][r] * invr[r];
        }
}

// ---------------- fallback (used only if ws_size too small) ----------------

__device__ __forceinline__ int swz9(int b) { return b ^ (((b >> 9) & 7) << 4); }
__device__ __forceinline__ int swz8f(int b) { return b ^ (((b >> 8) & 7) << 4); }

__global__ __launch_bounds__(256, 4)
void attn_fwd_v1(const float* __restrict__ Q, const float* __restrict__ K,
                 const float* __restrict__ V, float* __restrict__ Out) {
    __shared__ __align__(16) unsigned char lds[16384 + 16384 + 4 * 2048];
    unsigned char* KsB = lds;
    unsigned char* VtB = lds + 16384;
    const int tid = threadIdx.x;
    const int lane = tid & 63;
    const int w = tid >> 6;
    const int l15 = lane & 15;
    const int g = lane >> 4;
    const int qt = blockIdx.x;
    const int bh = blockIdx.y;
    const long long base = (long long)bh * SEQ * DDIM;
    const float* Qb = Q + base + (long long)(qt * 64 + w * 16) * DDIM;
    const float* Kb = K + base;
    const float* Vb = V + base;
    unsigned char* PB = lds + 32768 + w * 2048;
    bf16x8 qf[4];
#pragma unroll
    for (int ks = 0; ks < 4; ++ks) {
        const float* qp = Qb + l15 * DDIM + ks * 32 + g * 8;
        qf[ks] = cvt8s(*(const float4*)qp, *(const float4*)(qp + 4), QSCALE);
    }
    f32x4 o[8];
#pragma unroll
    for (int cb = 0; cb < 8; ++cb) { o[cb][0]=0.f; o[cb][1]=0.f; o[cb][2]=0.f; o[cb][3]=0.f; }
    float m_r[4] = { -INFINITY, -INFINITY, -INFINITY, -INFINITY };
    float l_r[4] = { 0.f, 0.f, 0.f, 0.f };
    for (int kt = 0; kt < SEQ / 64; ++kt) {
        __syncthreads();
#pragma unroll
        for (int it = 0; it < 4; ++it) {
            int chunk = tid + it * 256;
            int key = chunk >> 4;
            int dc = (chunk & 15) * 8;
            const float* kp = Kb + (long long)(kt * 64 + key) * DDIM + dc;
            *(bf16x8*)(KsB + swz9(key * 256 + dc * 2)) = cvt8s(*(const float4*)kp, *(const float4*)(kp + 4), 1.0f);
        }
#pragma unroll
        for (int it = 0; it < 8; ++it) {
            int task = w + it * 4;
            int kq = task >> 1;
            int dh = task & 1;
            int key = kq * 4 + g;
            int d0 = dh * 64 + l15 * 4;
            const float* vp = Vb + (long long)(kt * 64 + key) * DDIM + d0;
            float4 a = *(const float4*)vp;
            *(__bf16*)(VtB + swz8f((d0 + 0) * 128 + key * 2)) = (__bf16)a.x;
            *(__bf16*)(VtB + swz8f((d0 + 1) * 128 + key * 2)) = (__bf16)a.y;
            *(__bf16*)(VtB + swz8f((d0 + 2) * 128 + key * 2)) = (__bf16)a.z;
            *(__bf16*)(VtB + swz8f((d0 + 3) * 128 + key * 2)) = (__bf16)a.w;
        }
        __syncthreads();
        f32x4 sc[4];
#pragma unroll
        for (int c = 0; c < 4; ++c) {
            f32x4 acc; acc[0]=0.f; acc[1]=0.f; acc[2]=0.f; acc[3]=0.f;
#pragma unroll
            for (int ks = 0; ks < 4; ++ks) {
                bf16x8 bf = *(const bf16x8*)(KsB + swz9((c * 16 + l15) * 256 + (ks * 32 + g * 8) * 2));
                acc = __builtin_amdgcn_mfma_f32_16x16x32_bf16(qf[ks], bf, acc, 0, 0, 0);
            }
            sc[c] = acc;
        }
#pragma unroll
        for (int r = 0; r < 4; ++r) {
            float s0 = sc[0][r], s1 = sc[1][r], s2 = sc[2][r], s3 = sc[3][r];
            float mx = fmaxf(fmaxf(s0, s1), fmaxf(s2, s3));
            mx = fmaxf(mx, __shfl_xor(mx, 1));
            mx = fmaxf(mx, __shfl_xor(mx, 2));
            mx = fmaxf(mx, __shfl_xor(mx, 4));
            mx = fmaxf(mx, __shfl_xor(mx, 8));
            float mold = m_r[r];
            float mnew = fmaxf(mold, mx);
            float alpha = __builtin_amdgcn_exp2f(mold - mnew);
            float p0 = __builtin_amdgcn_exp2f(s0 - mnew);
            float p1 = __builtin_amdgcn_exp2f(s1 - mnew);
            float p2 = __builtin_amdgcn_exp2f(s2 - mnew);
            float p3 = __builtin_amdgcn_exp2f(s3 - mnew);
            float sum = (p0 + p1) + (p2 + p3);
            sum += __shfl_xor(sum, 1);
            sum += __shfl_xor(sum, 2);
            sum += __shfl_xor(sum, 4);
            sum += __shfl_xor(sum, 8);
            l_r[r] = l_r[r] * alpha + sum;
            m_r[r] = mnew;
#pragma unroll
            for (int cb = 0; cb < 8; ++cb) o[cb][r] *= alpha;
            int row = g * 4 + r;
            *(__bf16*)(PB + swz8f(row * 128 + (0 * 16 + l15) * 2)) = (__bf16)p0;
            *(__bf16*)(PB + swz8f(row * 128 + (1 * 16 + l15) * 2)) = (__bf16)p1;
            *(__bf16*)(PB + swz8f(row * 128 + (2 * 16 + l15) * 2)) = (__bf16)p2;
            *(__bf16*)(PB + swz8f(row * 128 + (3 * 16 + l15) * 2)) = (__bf16)p3;
        }
#pragma unroll
        for (int kk = 0; kk < 2; ++kk) {
            bf16x8 pa = *(const bf16x8*)(PB + swz8f(l15 * 128 + (kk * 32 + g * 8) * 2));
#pragma unroll
            for (int cb = 0; cb < 8; ++cb) {
                bf16x8 vb = *(const bf16x8*)(VtB + swz8f((cb * 16 + l15) * 128 + (kk * 32 + g * 8) * 2));
                o[cb] = __builtin_amdgcn_mfma_f32_16x16x32_bf16(pa, vb, o[cb], 0, 0, 0);
            }
        }
    }
    float* Ob = Out + base + (long long)(qt * 64 + w * 16) * DDIM;
#pragma unroll
    for (int r = 0; r < 4; ++r) {
        float inv = 1.0f / l_r[r];
        int row = g * 4 + r;
#pragma unroll
        for (int cb = 0; cb < 8; ++cb) Ob[row * DDIM + cb * 16 + l15] = o[cb][r] * inv;
    }
}

extern "C" void kernel_launch(void* const* d_in, const int* in_sizes, int n_in,
                              void* d_out, int out_size, void* d_ws, size_t ws_size,
                              hipStream_t stream) {
    const float* Q = (const float*)d_in[0];
    const float* K = (const float*)d_in[1];
    const float* V = (const float*)d_in[2];
    float* Out = (float*)d_out;

    if (ws_size >= (size_t)32 * 1024 * 1024) {
        unsigned char* ws = (unsigned char*)d_ws;
        unsigned char* kws = ws;
        unsigned char* vtws = ws + (size_t)16 * 1024 * 1024;
        prep_kv<<<1024, 256, 0, stream>>>(K, V, kws, vtws);
        attn_v16<<<512, 256, 0, stream>>>(Q, kws, vtws, Out);
    } else {
        attn_fwd_v1<<<dim3(32, 32), 256, 0, stream>>>(Q, K, V, Out);
    }
}